// Round 4
// baseline (401.437 us; speedup 1.0000x reference)
//
#include <hip/hip_runtime.h>
#include <stdint.h>
#include <stddef.h>

#define NN 50000
#define NE 600000
#define DI 512
#define DH 128
#define DO 40
#define MTOT (NN * DH)   // 6,400,000
#define NBLK ((NN + 255) / 256)   // 196 scan blocks

using int4v = __attribute__((ext_vector_type(4))) int;

// ---------------- threefry2x32 (exact JAX semantics) ----------------
__host__ __device__ inline uint32_t rotl32(uint32_t v, int d) {
  return (v << d) | (v >> (32 - d));
}

__host__ __device__ inline void threefry2x32(uint32_t k0, uint32_t k1,
                                             uint32_t c0, uint32_t c1,
                                             uint32_t* o0, uint32_t* o1) {
  uint32_t ks0 = k0, ks1 = k1, ks2 = k0 ^ k1 ^ 0x1BD11BDAu;
  uint32_t x0 = c0 + ks0, x1 = c1 + ks1;
  const int R0[4] = {13, 15, 26, 6};
  const int R1[4] = {17, 29, 16, 24};
#define TF_R4(R) { x0 += x1; x1 = rotl32(x1, R[0]); x1 ^= x0; \
                   x0 += x1; x1 = rotl32(x1, R[1]); x1 ^= x0; \
                   x0 += x1; x1 = rotl32(x1, R[2]); x1 ^= x0; \
                   x0 += x1; x1 = rotl32(x1, R[3]); x1 ^= x0; }
  TF_R4(R0); x0 += ks1; x1 += ks2 + 1u;
  TF_R4(R1); x0 += ks2; x1 += ks0 + 2u;
  TF_R4(R0); x0 += ks0; x1 += ks1 + 3u;
  TF_R4(R1); x0 += ks1; x1 += ks2 + 4u;
  TF_R4(R0); x0 += ks2; x1 += ks0 + 5u;
#undef TF_R4
  *o0 = x0; *o1 = x1;
}

// ---- BN column sums — EXACT round-7 grouping (200 blocks x 250 rows) ------
// NUMERICALLY LIVE: per-thread f64 add ORDER unchanged (rows ascending).
// Loads batched 10-deep to hide latency; loads are pure, order-inert.
__global__ void colsum_kernel(const float* __restrict__ x,
                              double* __restrict__ colsum) {
  int t = threadIdx.x;               // cols t and t+256
  int r0 = blockIdx.x * 250;
  double s0 = 0.0, s1 = 0.0;
  for (int r = r0; r < r0 + 250; r += 10) {
    double v0[10], v1[10];
#pragma unroll
    for (int u = 0; u < 10; ++u) {
      v0[u] = (double)x[(size_t)(r + u) * DI + t];
      v1[u] = (double)x[(size_t)(r + u) * DI + t + 256];
    }
#pragma unroll
    for (int u = 0; u < 10; ++u) {   // SAME sequential order as scalar loop
      s0 += v0[u];
      s1 += v1[u];
    }
  }
  unsafeAtomicAdd(&colsum[t], s0);
  unsafeAtomicAdd(&colsum[t + 256], s1);
}

__global__ void mean_finalize(double* __restrict__ colsum) {
  int c = blockIdx.x * blockDim.x + threadIdx.x;
  if (c < DI) colsum[c] = colsum[c] / (double)NN;
}

// ---- fused weight prep: MFMA B-fragments straight from float w + sum|w| ----
__device__ inline void wfuse_body(const float* __restrict__ w,
                                  uint32_t* __restrict__ frag,
                                  double* __restrict__ slot,
                                  int K, int C, int NT, int blk,
                                  double* red) {
  int steps = K >> 6;
  int total = steps * NT * 64 * 4;
  int idx = blk * 256 + threadIdx.x;
  double a = 0.0;
  if (idx < total) {
    int dw = idx & 3;
    int lane = (idx >> 2) & 63;
    int rest = idx >> 8;
    int t = rest % NT;
    int s = rest / NT;
    int n = t * 16 + (lane & 15);
    int kbase = s * 64 + (lane >> 4) * 16 + dw * 4;
    uint32_t v = 0;
    if (n < C) {
#pragma unroll
      for (int j = 0; j < 4; ++j) {
        float wv = w[(size_t)(kbase + j) * C + n];
        uint32_t sg = (uint8_t)(int8_t)((wv > 0.f) ? 1 : ((wv < 0.f) ? -1 : 0));
        v |= sg << (8 * j);
        a += (double)fabsf(wv);
      }
    }
    frag[idx] = v;
  }
  red[threadIdx.x] = a;
  __syncthreads();
  for (int ofs = 128; ofs > 0; ofs >>= 1) {
    if (threadIdx.x < ofs) red[threadIdx.x] += red[threadIdx.x + ofs];
    __syncthreads();
  }
  if (threadIdx.x == 0) unsafeAtomicAdd(slot, red[0]);
}

// one launch for all 3 layers: blocks [0,64) L0, [64,80) L1, [80,86) L2
__global__ void wfuse_all(const float* __restrict__ w0,
                          const float* __restrict__ w1,
                          const float* __restrict__ w2,
                          uint32_t* __restrict__ f0,
                          uint32_t* __restrict__ f1,
                          uint32_t* __restrict__ f2,
                          double* __restrict__ slots) {
  __shared__ double red[256];
  int b = blockIdx.x;
  if (b < 64)       wfuse_body(w0, f0, slots + 0, DI, DH, 8, b,      red);
  else if (b < 80)  wfuse_body(w1, f1, slots + 1, DH, DH, 8, b - 64, red);
  else              wfuse_body(w2, f2, slots + 2, DH, DO, 3, b - 80, red);
}

// ---------------- degree / CSR ----------------
__global__ void deg_edges(const int* __restrict__ ei, uint32_t* __restrict__ deg) {
  int e = blockIdx.x * blockDim.x + threadIdx.x;
  if (e < NE) atomicAdd(&deg[ei[e]], 1u);   // ei[0:E] = destinations
}

__global__ void scan_blocks(const uint32_t* __restrict__ deg,
                            uint32_t* __restrict__ rowptr,
                            uint32_t* __restrict__ bsum,
                            double* __restrict__ dinv) {
  __shared__ uint32_t bs[256];
  int t = threadIdx.x;
  int i = blockIdx.x * 256 + t;
  uint32_t v = (i < NN) ? deg[i] : 0u;
  if (i < NN) dinv[i] = 1.0 / sqrt((double)(v + 1u));   // +1 self-loop
  bs[t] = v;
  __syncthreads();
  for (int ofs = 1; ofs < 256; ofs <<= 1) {
    uint32_t add = (t >= ofs) ? bs[t - ofs] : 0u;
    __syncthreads();
    bs[t] += add;
    __syncthreads();
  }
  if (i < NN) rowptr[i] = bs[t] - v;     // exclusive within block
  if (t == 255) bsum[blockIdx.x] = bs[255];
}

__global__ void scan_bsum(const uint32_t* __restrict__ bsum,
                          uint32_t* __restrict__ base) {
  __shared__ uint32_t bs[256];
  int t = threadIdx.x;
  uint32_t v = (t < NBLK) ? bsum[t] : 0u;
  bs[t] = v;
  __syncthreads();
  for (int ofs = 1; ofs < 256; ofs <<= 1) {
    uint32_t add = (t >= ofs) ? bs[t - ofs] : 0u;
    __syncthreads();
    bs[t] += add;
    __syncthreads();
  }
  if (t < NBLK) base[t] = bs[t] - v;
}

__global__ void scan_addbase(uint32_t* __restrict__ rowptr,
                             const uint32_t* __restrict__ base) {
  int i = blockIdx.x * 256 + threadIdx.x;
  if (i < NN) rowptr[i] += base[blockIdx.x];
  if (i == 0) rowptr[NN] = NE;
}

__global__ void csr_fill(const int* __restrict__ ei,
                         const uint32_t* __restrict__ rowptr,
                         uint32_t* __restrict__ cursor,
                         int* __restrict__ csr_src) {
  int e = blockIdx.x * blockDim.x + threadIdx.x;
  if (e >= NE) return;
  int dst = ei[e], src = ei[NE + e];
  uint32_t pos = rowptr[dst] + atomicAdd(&cursor[dst], 1u);
  csr_src[pos] = src;
}

// ---------------- ternary GEMM via MFMA i8 16x16x64 -----------------------
template <int STEPS, int NT, int C, int SHIFT>
__global__ void gemm_mfma(const int8_t* __restrict__ S,
                          const uint32_t* __restrict__ frag,
                          int8_t* __restrict__ H) {
  extern __shared__ uint4 lb[];
  const int tot = STEPS * NT * 64;
  const uint4* fg = (const uint4*)frag;
  for (int i = threadIdx.x; i < tot; i += 256) lb[i] = fg[i];
  __syncthreads();
  const int lane = threadIdx.x & 63;
  const int wv = threadIdx.x >> 6;
  const int r0 = (blockIdx.x * 4 + wv) * 16;
  if (r0 >= NN) return;                 // NN % 16 == 0
  const int m = lane & 15, q = lane >> 4;
  const int K = STEPS * 64;
  const int8_t* sp = S + (size_t)(r0 + m) * K + q * 16;
  int4v acc[NT];
#pragma unroll
  for (int t = 0; t < NT; ++t) acc[t] = (int4v){0, 0, 0, 0};
#pragma unroll
  for (int s = 0; s < STEPS; ++s) {
    int4v a = *(const int4v*)(sp + (size_t)s * 64);
#pragma unroll
    for (int t = 0; t < NT; ++t) {
      int4v b = *(const int4v*)&lb[(s * NT + t) * 64 + lane];
      acc[t] = __builtin_amdgcn_mfma_i32_16x16x64_i8(a, b, acc[t], 0, 0, 0);
    }
  }
  int8_t* hp = H + (size_t)r0 * C;
#pragma unroll
  for (int t = 0; t < NT; ++t) {
    int n = t * 16 + m;
    if (n < C) {
#pragma unroll
      for (int r = 0; r < 4; ++r)
        hp[(size_t)(q * 4 + r) * C + n] = (int8_t)(acc[t][r] >> SHIFT);
    }
  }
}

// ---- layer-0 GEMM with bn_sign fused into the A-fragment load -------------
// A byte (row, k) = sign((double)x[row*512+k] - mean[k]) — EXACT bn_sign math,
// same packing order; S0 relay buffer eliminated (51 MB less traffic).
__global__ void gemm0_fused(const float* __restrict__ x,
                            const double* __restrict__ mean,
                            const uint32_t* __restrict__ frag,
                            int8_t* __restrict__ H) {
  extern __shared__ uint4 lb[];
  const int tot = 8 * 8 * 64;                       // 4096 uint4 = 64 KB
  const uint4* fg = (const uint4*)frag;
  for (int i = threadIdx.x; i < tot; i += 256) lb[i] = fg[i];
  __syncthreads();
  const int lane = threadIdx.x & 63;
  const int wv = threadIdx.x >> 6;
  const int r0 = (blockIdx.x * 4 + wv) * 16;
  if (r0 >= NN) return;
  const int m = lane & 15, q = lane >> 4;
  const float* xp = x + (size_t)(r0 + m) * DI + q * 16;
  const double* mp0 = mean + q * 16;
  int4v acc[8];
#pragma unroll
  for (int t = 0; t < 8; ++t) acc[t] = (int4v){0, 0, 0, 0};
#pragma unroll
  for (int s = 0; s < 8; ++s) {
    const float* xs = xp + s * 64;
    const double* mp = mp0 + s * 64;
    int4v a;
#pragma unroll
    for (int w4 = 0; w4 < 4; ++w4) {
      float4 f = *(const float4*)(xs + 4 * w4);
      double v0 = (double)f.x - mp[4 * w4 + 0];
      double v1 = (double)f.y - mp[4 * w4 + 1];
      double v2 = (double)f.z - mp[4 * w4 + 2];
      double v3 = (double)f.w - mp[4 * w4 + 3];
      uint32_t o = 0;
      o |= (uint8_t)(int8_t)((v0 > 0.0) ? 1 : ((v0 < 0.0) ? -1 : 0));
      o |= ((uint32_t)(uint8_t)(int8_t)((v1 > 0.0) ? 1 : ((v1 < 0.0) ? -1 : 0))) << 8;
      o |= ((uint32_t)(uint8_t)(int8_t)((v2 > 0.0) ? 1 : ((v2 < 0.0) ? -1 : 0))) << 16;
      o |= ((uint32_t)(uint8_t)(int8_t)((v3 > 0.0) ? 1 : ((v3 < 0.0) ? -1 : 0))) << 24;
      a[w4] = (int)o;
    }
#pragma unroll
    for (int t = 0; t < 8; ++t) {
      int4v b = *(const int4v*)&lb[(s * 8 + t) * 64 + lane];
      acc[t] = __builtin_amdgcn_mfma_i32_16x16x64_i8(a, b, acc[t], 0, 0, 0);
    }
  }
  int8_t* hp = H + (size_t)r0 * DH;
#pragma unroll
  for (int t = 0; t < 8; ++t) {
    int n = t * 16 + m;
#pragma unroll
    for (int r = 0; r < 4; ++r)
      hp[(size_t)(q * 4 + r) * DH + n] = (int8_t)(acc[t][r] >> 1);
  }
}

// ---- gather (C=128): ORDER-PRESERVING, 1-deep (shfl,load) prefetch --------
// FMA sequence per accumulator identical to round 7 (bit-exact f64 sums).
__global__ void gather128(const uint32_t* __restrict__ rowptr,
                          const int* __restrict__ csr_src,
                          const double* __restrict__ dinv,
                          const int8_t* __restrict__ H,
                          const float* __restrict__ b,
                          int8_t* __restrict__ Sout,
                          const double* __restrict__ wsum, double cnt,
                          uint32_t fk0, uint32_t fk1) {
  int d = (int)(((size_t)blockIdx.x * blockDim.x + threadIdx.x) >> 6);
  int lane = threadIdx.x & 63;
  if (d >= NN) return;
  const int g = lane >> 5, p = lane & 31;
  double a0 = 0.0, a1 = 0.0, a2 = 0.0, a3 = 0.0;
  const uint32_t e0 = rowptr[d];
  const int L = (int)(rowptr[d + 1] - e0) + 1;    // + self-loop (edge 0)
  for (int c0 = 0; c0 < L; c0 += 64) {
    const int n = min(64, L - c0);
    const int my = c0 + lane;
    int sidx = d;
    if (my > 0 && my < L) sidx = csr_src[e0 + my - 1];
    double wv = dinv[sidx];                       // sidx=d is valid fallback
    int t = 0;
    {
      int sA = 0, sB = 0; double wA = 0.0, wB = 0.0;
      uint32_t hA = 0, hB = 0;
      if (4 <= n) {                               // wave-uniform
        sA = __shfl(sidx, g);      wA = __shfl(wv, g);
        sB = __shfl(sidx, 2 + g);  wB = __shfl(wv, 2 + g);
        hA = *(const uint32_t*)(H + (size_t)sA * DH + 4 * p);
        hB = *(const uint32_t*)(H + (size_t)sB * DH + 4 * p);
      }
      for (; t + 4 <= n; t += 4) {
        const uint32_t cA = hA, cB = hB;
        const double vA = wA, vB = wB;
        if (t + 8 <= n) {                         // prefetch next pair
          sA = __shfl(sidx, t + 4 + g);  wA = __shfl(wv, t + 4 + g);
          sB = __shfl(sidx, t + 6 + g);  wB = __shfl(wv, t + 6 + g);
          hA = *(const uint32_t*)(H + (size_t)sA * DH + 4 * p);
          hB = *(const uint32_t*)(H + (size_t)sB * DH + 4 * p);
        }
        a0 += vA * (double)(int8_t)(cA);
        a1 += vA * (double)(int8_t)(cA >> 8);
        a2 += vA * (double)(int8_t)(cA >> 16);
        a3 += vA * (double)(int8_t)(cA >> 24);
        a0 += vB * (double)(int8_t)(cB);
        a1 += vB * (double)(int8_t)(cB >> 8);
        a2 += vB * (double)(int8_t)(cB >> 16);
        a3 += vB * (double)(int8_t)(cB >> 24);
      }
    }
    for (; t < n; t += 2) {                       // non-divergent tail
      const int j = t + g;
      const bool on = (j < n);
      const int jc = on ? j : 0;
      int s = __shfl(sidx, jc);
      double w = __shfl(wv, jc);
      w = on ? w : 0.0;
      uint32_t hv = *(const uint32_t*)(H + (size_t)s * DH + 4 * p);
      a0 += w * (double)(int8_t)(hv);
      a1 += w * (double)(int8_t)(hv >> 8);
      a2 += w * (double)(int8_t)(hv >> 16);
      a3 += w * (double)(int8_t)(hv >> 24);
    }
  }
  a0 += __shfl_xor(a0, 32);
  a1 += __shfl_xor(a1, 32);
  a2 += __shfl_xor(a2, 32);
  a3 += __shfl_xor(a3, 32);
  double sc = (wsum[0] / cnt) * dinv[d];
  int ch = 4 * p + 2 * g;
  int j0 = d * DH + ch;
  double va = sc * ((g == 0) ? a0 : a2) + (double)b[ch];
  double vb = sc * ((g == 0) ? a1 : a3) + (double)b[ch + 1];
  int s0 = (va > 0.0) ? 1 : ((va < 0.0) ? -1 : 0);
  int s1 = (vb > 0.0) ? 1 : ((vb < 0.0) ? -1 : 0);
  uint32_t r0, r1, bits0, bits1;
  threefry2x32(fk0, fk1, 0u, (uint32_t)j0, &r0, &r1);
  bits0 = r0 ^ r1;
  threefry2x32(fk0, fk1, 0u, (uint32_t)(j0 + 1), &r0, &r1);
  bits1 = r0 ^ r1;
  float u0 = __uint_as_float((bits0 >> 9) | 0x3f800000u) - 1.0f;
  float u1 = __uint_as_float((bits1 >> 9) | 0x3f800000u) - 1.0f;
  uint8_t o0 = (u0 < 0.5f) ? (uint8_t)(int8_t)s0 : (uint8_t)0;
  uint8_t o1 = (u1 < 0.5f) ? (uint8_t)(int8_t)s1 : (uint8_t)0;
  *(uint16_t*)(Sout + j0) = (uint16_t)(o0 | ((uint16_t)o1 << 8));
}

// ---- gather (C=40): ORDER-PRESERVING, 1-deep prefetch, fused log_softmax --
__global__ void gather40_lsm(const uint32_t* __restrict__ rowptr,
                             const int* __restrict__ csr_src,
                             const double* __restrict__ dinv,
                             const int8_t* __restrict__ H,
                             const float* __restrict__ b2,
                             const double* __restrict__ wsum,
                             float* __restrict__ out) {
  int d = (int)(((size_t)blockIdx.x * blockDim.x + threadIdx.x) >> 6);
  int lane = threadIdx.x & 63;
  if (d >= NN) return;
  const int g = lane >> 5, p = lane & 31;
  const bool act = (p < 20);
  double a0 = 0.0, a1 = 0.0;
  const uint32_t e0 = rowptr[d];
  const int L = (int)(rowptr[d + 1] - e0) + 1;
  for (int c0 = 0; c0 < L; c0 += 64) {
    const int n = min(64, L - c0);
    const int my = c0 + lane;
    int sidx = d;
    if (my > 0 && my < L) sidx = csr_src[e0 + my - 1];
    double wv = dinv[sidx];
    int t = 0;
    {
      int sA = 0, sB = 0; double wA = 0.0, wB = 0.0;
      uint16_t hA = 0, hB = 0;
      if (4 <= n) {
        sA = __shfl(sidx, g);      wA = __shfl(wv, g);
        sB = __shfl(sidx, 2 + g);  wB = __shfl(wv, 2 + g);
        if (act) {
          hA = *(const uint16_t*)(H + (size_t)sA * DO + 2 * p);
          hB = *(const uint16_t*)(H + (size_t)sB * DO + 2 * p);
        }
      }
      for (; t + 4 <= n; t += 4) {
        const uint16_t cA = hA, cB = hB;
        const double vA = wA, vB = wB;
        if (t + 8 <= n) {
          sA = __shfl(sidx, t + 4 + g);  wA = __shfl(wv, t + 4 + g);
          sB = __shfl(sidx, t + 6 + g);  wB = __shfl(wv, t + 6 + g);
          if (act) {
            hA = *(const uint16_t*)(H + (size_t)sA * DO + 2 * p);
            hB = *(const uint16_t*)(H + (size_t)sB * DO + 2 * p);
          }
        }
        if (act) {
          a0 += vA * (double)(int8_t)(cA);
          a1 += vA * (double)(int8_t)(cA >> 8);
          a0 += vB * (double)(int8_t)(cB);
          a1 += vB * (double)(int8_t)(cB >> 8);
        }
      }
    }
    for (; t < n; t += 2) {
      const int j = t + g;
      const bool on = (j < n);
      const int jc = on ? j : 0;
      int s = __shfl(sidx, jc);
      double w = __shfl(wv, jc);
      w = on ? w : 0.0;
      if (act) {
        uint16_t hv = *(const uint16_t*)(H + (size_t)s * DO + 2 * p);
        a0 += w * (double)(int8_t)(hv);
        a1 += w * (double)(int8_t)(hv >> 8);
      }
    }
  }
  a0 += __shfl_xor(a0, 32);
  a1 += __shfl_xor(a1, 32);
  double sc = (wsum[0] / (double)(DH * DO)) * dinv[d];
  const bool lead = (g == 0) && act;
  double v0 = 0.0, v1 = 0.0;
  if (act) {
    v0 = sc * a0 + (double)b2[2 * p];
    v1 = sc * a1 + (double)b2[2 * p + 1];
  }
  double mx = lead ? fmax(v0, v1) : -1.0e300;
  for (int ofs = 32; ofs > 0; ofs >>= 1) mx = fmax(mx, __shfl_xor(mx, ofs));
  float ex = lead ? (expf((float)(v0 - mx)) + expf((float)(v1 - mx))) : 0.f;
  for (int ofs = 32; ofs > 0; ofs >>= 1) ex += __shfl_xor(ex, ofs);
  float l = logf(ex);
  if (lead) {
    float2 o = make_float2((float)(v0 - mx) - l, (float)(v1 - mx) - l);
    *(float2*)(out + (size_t)d * DO + 2 * p) = o;
  }
}

// ---------------- launch ----------------
extern "C" void kernel_launch(void* const* d_in, const int* in_sizes, int n_in,
                              void* d_out, int out_size, void* d_ws, size_t ws_size,
                              hipStream_t stream) {
  (void)in_sizes; (void)n_in; (void)out_size; (void)ws_size;
  const float* x  = (const float*)d_in[0];
  const int*   ei = (const int*)d_in[1];
  const float* w0 = (const float*)d_in[2];
  const float* b0 = (const float*)d_in[3];
  const float* w1 = (const float*)d_in[4];
  const float* b1 = (const float*)d_in[5];
  const float* w2 = (const float*)d_in[6];
  const float* b2 = (const float*)d_in[7];
  float* out = (float*)d_out;

  // ---- workspace carve-up (~17 MB)
  char* wsb = (char*)d_ws;
  double*   mean_d = (double*)wsb;                    // [512] col sums->means
  double*   wsum_d = (double*)(wsb + 4096);           // [3]            pad->4224
  uint32_t* deg_e  = (uint32_t*)(wsb + 4224);         // [NN] edge-only degree
  uint32_t* cursor = (uint32_t*)(wsb + 204224);       // [NN] fill cursors
  // bytes [0, 404224) are zeroed each call
  size_t cur = 404480;
  uint32_t* rowptr = (uint32_t*)(wsb + cur); cur += 200064;   // [NN+1]
  double*   dinv_d = (double*)(wsb + cur);  cur += 400000;
  cur = (cur + 255) & ~255ull;
  uint32_t* bsum = (uint32_t*)(wsb + cur); cur += 1024;       // [NBLK]
  uint32_t* base = (uint32_t*)(wsb + cur); cur += 1024;       // [NBLK]
  int*    csr_src = (int*)(wsb + cur);    cur += (size_t)NE * 4;   // 2.4 MB
  cur = (cur + 255) & ~255ull;
  uint32_t* FR0 = (uint32_t*)(wsb + cur); cur += 8 * 8 * 64 * 16;  // 64 KB
  uint32_t* FR1 = (uint32_t*)(wsb + cur); cur += 2 * 8 * 64 * 16;  // 16 KB
  uint32_t* FR2 = (uint32_t*)(wsb + cur); cur += 2 * 3 * 64 * 16;  // 6 KB
  int8_t* S1  = (int8_t*)(wsb + cur); cur += (size_t)MTOT;         // 6.4 MB
  cur = (cur + 255) & ~255ull;
  int8_t* H8 = (int8_t*)(wsb + cur); cur += (size_t)MTOT;          // 6.4 MB

  // fold_in(key(42), i): key=(0,42); folded = threefry(key, (0,i)) full output
  uint32_t fkA0, fkA1, fkB0, fkB1;
  threefry2x32(0u, 42u, 0u, 0u, &fkA0, &fkA1);
  threefry2x32(0u, 42u, 0u, 1u, &fkB0, &fkB1);

  // zero mean/wsum/deg/cursor (ws is poisoned 0xAA before every call)
  hipMemsetAsync(wsb, 0, 404224, stream);

  colsum_kernel<<<200, 256, 0, stream>>>(x, mean_d);
  mean_finalize<<<2, 256, 0, stream>>>(mean_d);
  wfuse_all<<<86, 256, 0, stream>>>(w0, w1, w2, FR0, FR1, FR2, wsum_d);
  deg_edges<<<(NE + 255) / 256, 256, 0, stream>>>(ei, deg_e);
  scan_blocks<<<NBLK, 256, 0, stream>>>(deg_e, rowptr, bsum, dinv_d);
  scan_bsum<<<1, 256, 0, stream>>>(bsum, base);
  scan_addbase<<<NBLK, 256, 0, stream>>>(rowptr, base);
  csr_fill<<<(NE + 255) / 256, 256, 0, stream>>>(ei, rowptr, cursor, csr_src);

  const int gemm_blocks = (NN / 16 + 3) / 4;            // 782 (4 waves x 16 rows)
  const int node_blocks = (NN * 64) / 256 + 1;          // 12501 waves >= NN
  const size_t sh0 = 8 * 8 * 64 * 16;                   // 64 KB
  const size_t sh1 = 2 * 8 * 64 * 16;                   // 16 KB
  const size_t sh2 = 2 * 3 * 64 * 16;                   // 6 KB

  // layer 0: K=512 -> DH, bn_sign fused (H = h/2 exact; x2 folded into cnt)
  gemm0_fused<<<gemm_blocks, 256, sh0, stream>>>(x, mean_d, FR0, H8);
  gather128<<<node_blocks, 256, 0, stream>>>(rowptr, csr_src, dinv_d, H8, b0, S1,
                                             wsum_d + 0, (double)(DI * DH / 2),
                                             fkA0, fkA1);

  // layer 1: K=128 -> DH
  gemm_mfma<2, 8, DH, 0><<<gemm_blocks, 256, sh1, stream>>>(S1, FR1, H8);
  gather128<<<node_blocks, 256, 0, stream>>>(rowptr, csr_src, dinv_d, H8, b1, S1,
                                             wsum_d + 1, (double)(DH * DH),
                                             fkB0, fkB1);

  // layer 2: K=128 -> DO, fused log_softmax
  gemm_mfma<2, 3, DO, 0><<<gemm_blocks, 256, sh2, stream>>>(S1, FR2, H8);
  gather40_lsm<<<node_blocks, 256, 0, stream>>>(rowptr, csr_src, dinv_d, H8, b2,
                                                wsum_d + 2, out);
}

// Round 5
// 388.120 us; speedup vs baseline: 1.0343x; 1.0343x over previous
//
#include <hip/hip_runtime.h>
#include <stdint.h>
#include <stddef.h>

#define NN 50000
#define NE 600000
#define DI 512
#define DH 128
#define DO 40
#define MTOT (NN * DH)   // 6,400,000
#define NBLK ((NN + 255) / 256)   // 196 scan blocks
#define DEGB ((NE + 255) / 256)   // 2344 deg blocks

using int4v = __attribute__((ext_vector_type(4))) int;

// ---------------- threefry2x32 (exact JAX semantics) ----------------
__host__ __device__ inline uint32_t rotl32(uint32_t v, int d) {
  return (v << d) | (v >> (32 - d));
}

__host__ __device__ inline void threefry2x32(uint32_t k0, uint32_t k1,
                                             uint32_t c0, uint32_t c1,
                                             uint32_t* o0, uint32_t* o1) {
  uint32_t ks0 = k0, ks1 = k1, ks2 = k0 ^ k1 ^ 0x1BD11BDAu;
  uint32_t x0 = c0 + ks0, x1 = c1 + ks1;
  const int R0[4] = {13, 15, 26, 6};
  const int R1[4] = {17, 29, 16, 24};
#define TF_R4(R) { x0 += x1; x1 = rotl32(x1, R[0]); x1 ^= x0; \
                   x0 += x1; x1 = rotl32(x1, R[1]); x1 ^= x0; \
                   x0 += x1; x1 = rotl32(x1, R[2]); x1 ^= x0; \
                   x0 += x1; x1 = rotl32(x1, R[3]); x1 ^= x0; }
  TF_R4(R0); x0 += ks1; x1 += ks2 + 1u;
  TF_R4(R1); x0 += ks2; x1 += ks0 + 2u;
  TF_R4(R0); x0 += ks0; x1 += ks1 + 3u;
  TF_R4(R1); x0 += ks1; x1 += ks2 + 4u;
  TF_R4(R0); x0 += ks2; x1 += ks0 + 5u;
#undef TF_R4
  *o0 = x0; *o1 = x1;
}

// ---- BN column sums body — EXACT round-7 grouping (200 blocks x 250 rows) --
// NUMERICALLY LIVE: per-thread f64 add ORDER unchanged (rows ascending).
__device__ inline void colsum_body(const float* __restrict__ x,
                                   double* __restrict__ colsum, int blk) {
  int t = threadIdx.x;               // cols t and t+256
  int r0 = blk * 250;
  double s0 = 0.0, s1 = 0.0;
  for (int r = r0; r < r0 + 250; r += 10) {
    double v0[10], v1[10];
#pragma unroll
    for (int u = 0; u < 10; ++u) {
      v0[u] = (double)x[(size_t)(r + u) * DI + t];
      v1[u] = (double)x[(size_t)(r + u) * DI + t + 256];
    }
#pragma unroll
    for (int u = 0; u < 10; ++u) {   // SAME sequential order as scalar loop
      s0 += v0[u];
      s1 += v1[u];
    }
  }
  unsafeAtomicAdd(&colsum[t], s0);
  unsafeAtomicAdd(&colsum[t + 256], s1);
}

// ---- fused weight prep body: MFMA B-fragments from float w + sum|w| -------
__device__ inline void wfuse_body(const float* __restrict__ w,
                                  uint32_t* __restrict__ frag,
                                  double* __restrict__ slot,
                                  int K, int C, int NT, int blk,
                                  double* red) {
  int steps = K >> 6;
  int total = steps * NT * 64 * 4;
  int idx = blk * 256 + threadIdx.x;
  double a = 0.0;
  if (idx < total) {
    int dw = idx & 3;
    int lane = (idx >> 2) & 63;
    int rest = idx >> 8;
    int t = rest % NT;
    int s = rest / NT;
    int n = t * 16 + (lane & 15);
    int kbase = s * 64 + (lane >> 4) * 16 + dw * 4;
    uint32_t v = 0;
    if (n < C) {
#pragma unroll
      for (int j = 0; j < 4; ++j) {
        float wv = w[(size_t)(kbase + j) * C + n];
        uint32_t sg = (uint8_t)(int8_t)((wv > 0.f) ? 1 : ((wv < 0.f) ? -1 : 0));
        v |= sg << (8 * j);
        a += (double)fabsf(wv);
      }
    }
    frag[idx] = v;
  }
  red[threadIdx.x] = a;
  __syncthreads();
  for (int ofs = 128; ofs > 0; ofs >>= 1) {
    if (threadIdx.x < ofs) red[threadIdx.x] += red[threadIdx.x + ofs];
    __syncthreads();
  }
  if (threadIdx.x == 0) unsafeAtomicAdd(slot, red[0]);
}

// ---- MEGA-1: colsum [0,200) || deg_edges [200,2544) || wfuse [2544,2630) ---
// Independent subtasks; block-range dispatch overlaps colsum's low occupancy
// with the edge-degree atomics and weight prep.
__global__ void prologue_fused(const float* __restrict__ x,
                               double* __restrict__ colsum,
                               const int* __restrict__ ei,
                               uint32_t* __restrict__ deg,
                               const float* __restrict__ w0,
                               const float* __restrict__ w1,
                               const float* __restrict__ w2,
                               uint32_t* __restrict__ f0,
                               uint32_t* __restrict__ f1,
                               uint32_t* __restrict__ f2,
                               double* __restrict__ slots) {
  __shared__ double red[256];
  int b = blockIdx.x;
  if (b < 200) {
    colsum_body(x, colsum, b);
  } else if (b < 200 + DEGB) {
    int e = (b - 200) * 256 + threadIdx.x;
    if (e < NE) atomicAdd(&deg[ei[e]], 1u);   // ei[0:E] = destinations
  } else {
    int wb = b - (200 + DEGB);
    if (wb < 64)       wfuse_body(w0, f0, slots + 0, DI, DH, 8, wb,      red);
    else if (wb < 80)  wfuse_body(w1, f1, slots + 1, DH, DH, 8, wb - 64, red);
    else               wfuse_body(w2, f2, slots + 2, DH, DO, 3, wb - 80, red);
  }
}

// ---- MEGA-2: scan_blocks [0,196) || mean_finalize [196,198) ----------------
__global__ void scan_mean(const uint32_t* __restrict__ deg,
                          uint32_t* __restrict__ rowptr,
                          uint32_t* __restrict__ bsum,
                          double* __restrict__ dinv,
                          double* __restrict__ colsum) {
  __shared__ uint32_t bs[256];
  int b = blockIdx.x;
  int t = threadIdx.x;
  if (b < NBLK) {
    int i = b * 256 + t;
    uint32_t v = (i < NN) ? deg[i] : 0u;
    if (i < NN) dinv[i] = 1.0 / sqrt((double)(v + 1u));   // +1 self-loop
    bs[t] = v;
    __syncthreads();
    for (int ofs = 1; ofs < 256; ofs <<= 1) {
      uint32_t add = (t >= ofs) ? bs[t - ofs] : 0u;
      __syncthreads();
      bs[t] += add;
      __syncthreads();
    }
    if (i < NN) rowptr[i] = bs[t] - v;     // exclusive within block (pre-base)
    if (t == 255) bsum[b] = bs[255];
  } else {
    int c = (b - NBLK) * 256 + t;
    if (c < DI) colsum[c] = colsum[c] / (double)NN;
  }
}

__global__ void scan_bsum(const uint32_t* __restrict__ bsum,
                          uint32_t* __restrict__ base) {
  __shared__ uint32_t bs[256];
  int t = threadIdx.x;
  uint32_t v = (t < NBLK) ? bsum[t] : 0u;
  bs[t] = v;
  __syncthreads();
  for (int ofs = 1; ofs < 256; ofs <<= 1) {
    uint32_t add = (t >= ofs) ? bs[t - ofs] : 0u;
    __syncthreads();
    bs[t] += add;
    __syncthreads();
  }
  if (t < NBLK) base[t] = bs[t] - v;
}

// csr_fill with scan_addbase folded in: global pos = rowptr[dst]+base[dst>>8]
__global__ void csr_fill(const int* __restrict__ ei,
                         const uint32_t* __restrict__ rowptr,
                         const uint32_t* __restrict__ base,
                         uint32_t* __restrict__ cursor,
                         int* __restrict__ csr_src) {
  int e = blockIdx.x * blockDim.x + threadIdx.x;
  if (e >= NE) return;
  int dst = ei[e], src = ei[NE + e];
  uint32_t pos = rowptr[dst] + base[dst >> 8] + atomicAdd(&cursor[dst], 1u);
  csr_src[pos] = src;
}

// ---------------- ternary GEMM via MFMA i8 16x16x64 -----------------------
template <int STEPS, int NT, int C, int SHIFT>
__global__ void gemm_mfma(const int8_t* __restrict__ S,
                          const uint32_t* __restrict__ frag,
                          int8_t* __restrict__ H) {
  extern __shared__ uint4 lb[];
  const int tot = STEPS * NT * 64;
  const uint4* fg = (const uint4*)frag;
  for (int i = threadIdx.x; i < tot; i += 256) lb[i] = fg[i];
  __syncthreads();
  const int lane = threadIdx.x & 63;
  const int wv = threadIdx.x >> 6;
  const int r0 = (blockIdx.x * 4 + wv) * 16;
  if (r0 >= NN) return;                 // NN % 16 == 0
  const int m = lane & 15, q = lane >> 4;
  const int K = STEPS * 64;
  const int8_t* sp = S + (size_t)(r0 + m) * K + q * 16;
  int4v acc[NT];
#pragma unroll
  for (int t = 0; t < NT; ++t) acc[t] = (int4v){0, 0, 0, 0};
#pragma unroll
  for (int s = 0; s < STEPS; ++s) {
    int4v a = *(const int4v*)(sp + (size_t)s * 64);
#pragma unroll
    for (int t = 0; t < NT; ++t) {
      int4v b = *(const int4v*)&lb[(s * NT + t) * 64 + lane];
      acc[t] = __builtin_amdgcn_mfma_i32_16x16x64_i8(a, b, acc[t], 0, 0, 0);
    }
  }
  int8_t* hp = H + (size_t)r0 * C;
#pragma unroll
  for (int t = 0; t < NT; ++t) {
    int n = t * 16 + m;
    if (n < C) {
#pragma unroll
      for (int r = 0; r < 4; ++r)
        hp[(size_t)(q * 4 + r) * C + n] = (int8_t)(acc[t][r] >> SHIFT);
    }
  }
}

// ---- layer-0 GEMM with bn_sign fused into the A-fragment load -------------
// A byte (row, k) = sign((double)x[row*512+k] - mean[k]) — EXACT bn_sign math,
// same packing order; S0 relay buffer eliminated.
__global__ void gemm0_fused(const float* __restrict__ x,
                            const double* __restrict__ mean,
                            const uint32_t* __restrict__ frag,
                            int8_t* __restrict__ H) {
  extern __shared__ uint4 lb[];
  const int tot = 8 * 8 * 64;                       // 4096 uint4 = 64 KB
  const uint4* fg = (const uint4*)frag;
  for (int i = threadIdx.x; i < tot; i += 256) lb[i] = fg[i];
  __syncthreads();
  const int lane = threadIdx.x & 63;
  const int wv = threadIdx.x >> 6;
  const int r0 = (blockIdx.x * 4 + wv) * 16;
  if (r0 >= NN) return;
  const int m = lane & 15, q = lane >> 4;
  const float* xp = x + (size_t)(r0 + m) * DI + q * 16;
  const double* mp0 = mean + q * 16;
  int4v acc[8];
#pragma unroll
  for (int t = 0; t < 8; ++t) acc[t] = (int4v){0, 0, 0, 0};
#pragma unroll
  for (int s = 0; s < 8; ++s) {
    const float* xs = xp + s * 64;
    const double* mp = mp0 + s * 64;
    int4v a;
#pragma unroll
    for (int w4 = 0; w4 < 4; ++w4) {
      float4 f = *(const float4*)(xs + 4 * w4);
      double v0 = (double)f.x - mp[4 * w4 + 0];
      double v1 = (double)f.y - mp[4 * w4 + 1];
      double v2 = (double)f.z - mp[4 * w4 + 2];
      double v3 = (double)f.w - mp[4 * w4 + 3];
      uint32_t o = 0;
      o |= (uint8_t)(int8_t)((v0 > 0.0) ? 1 : ((v0 < 0.0) ? -1 : 0));
      o |= ((uint32_t)(uint8_t)(int8_t)((v1 > 0.0) ? 1 : ((v1 < 0.0) ? -1 : 0))) << 8;
      o |= ((uint32_t)(uint8_t)(int8_t)((v2 > 0.0) ? 1 : ((v2 < 0.0) ? -1 : 0))) << 16;
      o |= ((uint32_t)(uint8_t)(int8_t)((v3 > 0.0) ? 1 : ((v3 < 0.0) ? -1 : 0))) << 24;
      a[w4] = (int)o;
    }
#pragma unroll
    for (int t = 0; t < 8; ++t) {
      int4v b = *(const int4v*)&lb[(s * 8 + t) * 64 + lane];
      acc[t] = __builtin_amdgcn_mfma_i32_16x16x64_i8(a, b, acc[t], 0, 0, 0);
    }
  }
  int8_t* hp = H + (size_t)r0 * DH;
#pragma unroll
  for (int t = 0; t < 8; ++t) {
    int n = t * 16 + m;
#pragma unroll
    for (int r = 0; r < 4; ++r)
      hp[(size_t)(q * 4 + r) * DH + n] = (int8_t)(acc[t][r] >> 1);
  }
}

// ---- gather (C=128): ORDER-PRESERVING, 1-deep prefetch, base folded in ----
__global__ void gather128(const uint32_t* __restrict__ rowptr,
                          const uint32_t* __restrict__ base,
                          const int* __restrict__ csr_src,
                          const double* __restrict__ dinv,
                          const int8_t* __restrict__ H,
                          const float* __restrict__ b,
                          int8_t* __restrict__ Sout,
                          const double* __restrict__ wsum, double cnt,
                          uint32_t fk0, uint32_t fk1) {
  int d = (int)(((size_t)blockIdx.x * blockDim.x + threadIdx.x) >> 6);
  int lane = threadIdx.x & 63;
  if (d >= NN) return;
  const int g = lane >> 5, p = lane & 31;
  double a0 = 0.0, a1 = 0.0, a2 = 0.0, a3 = 0.0;
  const uint32_t e0 = rowptr[d] + base[d >> 8];
  const uint32_t e1 = (d + 1 < NN) ? (rowptr[d + 1] + base[(d + 1) >> 8]) : NE;
  const int L = (int)(e1 - e0) + 1;               // + self-loop (edge 0)
  for (int c0 = 0; c0 < L; c0 += 64) {
    const int n = min(64, L - c0);
    const int my = c0 + lane;
    int sidx = d;
    if (my > 0 && my < L) sidx = csr_src[e0 + my - 1];
    double wv = dinv[sidx];                       // sidx=d is valid fallback
    int t = 0;
    {
      int sA = 0, sB = 0; double wA = 0.0, wB = 0.0;
      uint32_t hA = 0, hB = 0;
      if (4 <= n) {                               // wave-uniform
        sA = __shfl(sidx, g);      wA = __shfl(wv, g);
        sB = __shfl(sidx, 2 + g);  wB = __shfl(wv, 2 + g);
        hA = *(const uint32_t*)(H + (size_t)sA * DH + 4 * p);
        hB = *(const uint32_t*)(H + (size_t)sB * DH + 4 * p);
      }
      for (; t + 4 <= n; t += 4) {
        const uint32_t cA = hA, cB = hB;
        const double vA = wA, vB = wB;
        if (t + 8 <= n) {                         // prefetch next pair
          sA = __shfl(sidx, t + 4 + g);  wA = __shfl(wv, t + 4 + g);
          sB = __shfl(sidx, t + 6 + g);  wB = __shfl(wv, t + 6 + g);
          hA = *(const uint32_t*)(H + (size_t)sA * DH + 4 * p);
          hB = *(const uint32_t*)(H + (size_t)sB * DH + 4 * p);
        }
        a0 += vA * (double)(int8_t)(cA);
        a1 += vA * (double)(int8_t)(cA >> 8);
        a2 += vA * (double)(int8_t)(cA >> 16);
        a3 += vA * (double)(int8_t)(cA >> 24);
        a0 += vB * (double)(int8_t)(cB);
        a1 += vB * (double)(int8_t)(cB >> 8);
        a2 += vB * (double)(int8_t)(cB >> 16);
        a3 += vB * (double)(int8_t)(cB >> 24);
      }
    }
    for (; t < n; t += 2) {                       // non-divergent tail
      const int j = t + g;
      const bool on = (j < n);
      const int jc = on ? j : 0;
      int s = __shfl(sidx, jc);
      double w = __shfl(wv, jc);
      w = on ? w : 0.0;
      uint32_t hv = *(const uint32_t*)(H + (size_t)s * DH + 4 * p);
      a0 += w * (double)(int8_t)(hv);
      a1 += w * (double)(int8_t)(hv >> 8);
      a2 += w * (double)(int8_t)(hv >> 16);
      a3 += w * (double)(int8_t)(hv >> 24);
    }
  }
  a0 += __shfl_xor(a0, 32);
  a1 += __shfl_xor(a1, 32);
  a2 += __shfl_xor(a2, 32);
  a3 += __shfl_xor(a3, 32);
  double sc = (wsum[0] / cnt) * dinv[d];
  int ch = 4 * p + 2 * g;
  int j0 = d * DH + ch;
  double va = sc * ((g == 0) ? a0 : a2) + (double)b[ch];
  double vb = sc * ((g == 0) ? a1 : a3) + (double)b[ch + 1];
  int s0 = (va > 0.0) ? 1 : ((va < 0.0) ? -1 : 0);
  int s1 = (vb > 0.0) ? 1 : ((vb < 0.0) ? -1 : 0);
  uint32_t r0, r1, bits0, bits1;
  threefry2x32(fk0, fk1, 0u, (uint32_t)j0, &r0, &r1);
  bits0 = r0 ^ r1;
  threefry2x32(fk0, fk1, 0u, (uint32_t)(j0 + 1), &r0, &r1);
  bits1 = r0 ^ r1;
  float u0 = __uint_as_float((bits0 >> 9) | 0x3f800000u) - 1.0f;
  float u1 = __uint_as_float((bits1 >> 9) | 0x3f800000u) - 1.0f;
  uint8_t o0 = (u0 < 0.5f) ? (uint8_t)(int8_t)s0 : (uint8_t)0;
  uint8_t o1 = (u1 < 0.5f) ? (uint8_t)(int8_t)s1 : (uint8_t)0;
  *(uint16_t*)(Sout + j0) = (uint16_t)(o0 | ((uint16_t)o1 << 8));
}

// ---- gather (C=40): ORDER-PRESERVING, base folded in, fused log_softmax ---
__global__ void gather40_lsm(const uint32_t* __restrict__ rowptr,
                             const uint32_t* __restrict__ base,
                             const int* __restrict__ csr_src,
                             const double* __restrict__ dinv,
                             const int8_t* __restrict__ H,
                             const float* __restrict__ b2,
                             const double* __restrict__ wsum,
                             float* __restrict__ out) {
  int d = (int)(((size_t)blockIdx.x * blockDim.x + threadIdx.x) >> 6);
  int lane = threadIdx.x & 63;
  if (d >= NN) return;
  const int g = lane >> 5, p = lane & 31;
  const bool act = (p < 20);
  double a0 = 0.0, a1 = 0.0;
  const uint32_t e0 = rowptr[d] + base[d >> 8];
  const uint32_t e1 = (d + 1 < NN) ? (rowptr[d + 1] + base[(d + 1) >> 8]) : NE;
  const int L = (int)(e1 - e0) + 1;
  for (int c0 = 0; c0 < L; c0 += 64) {
    const int n = min(64, L - c0);
    const int my = c0 + lane;
    int sidx = d;
    if (my > 0 && my < L) sidx = csr_src[e0 + my - 1];
    double wv = dinv[sidx];
    int t = 0;
    {
      int sA = 0, sB = 0; double wA = 0.0, wB = 0.0;
      uint16_t hA = 0, hB = 0;
      if (4 <= n) {
        sA = __shfl(sidx, g);      wA = __shfl(wv, g);
        sB = __shfl(sidx, 2 + g);  wB = __shfl(wv, 2 + g);
        if (act) {
          hA = *(const uint16_t*)(H + (size_t)sA * DO + 2 * p);
          hB = *(const uint16_t*)(H + (size_t)sB * DO + 2 * p);
        }
      }
      for (; t + 4 <= n; t += 4) {
        const uint16_t cA = hA, cB = hB;
        const double vA = wA, vB = wB;
        if (t + 8 <= n) {
          sA = __shfl(sidx, t + 4 + g);  wA = __shfl(wv, t + 4 + g);
          sB = __shfl(sidx, t + 6 + g);  wB = __shfl(wv, t + 6 + g);
          if (act) {
            hA = *(const uint16_t*)(H + (size_t)sA * DO + 2 * p);
            hB = *(const uint16_t*)(H + (size_t)sB * DO + 2 * p);
          }
        }
        if (act) {
          a0 += vA * (double)(int8_t)(cA);
          a1 += vA * (double)(int8_t)(cA >> 8);
          a0 += vB * (double)(int8_t)(cB);
          a1 += vB * (double)(int8_t)(cB >> 8);
        }
      }
    }
    for (; t < n; t += 2) {
      const int j = t + g;
      const bool on = (j < n);
      const int jc = on ? j : 0;
      int s = __shfl(sidx, jc);
      double w = __shfl(wv, jc);
      w = on ? w : 0.0;
      if (act) {
        uint16_t hv = *(const uint16_t*)(H + (size_t)s * DO + 2 * p);
        a0 += w * (double)(int8_t)(hv);
        a1 += w * (double)(int8_t)(hv >> 8);
      }
    }
  }
  a0 += __shfl_xor(a0, 32);
  a1 += __shfl_xor(a1, 32);
  double sc = (wsum[0] / (double)(DH * DO)) * dinv[d];
  const bool lead = (g == 0) && act;
  double v0 = 0.0, v1 = 0.0;
  if (act) {
    v0 = sc * a0 + (double)b2[2 * p];
    v1 = sc * a1 + (double)b2[2 * p + 1];
  }
  double mx = lead ? fmax(v0, v1) : -1.0e300;
  for (int ofs = 32; ofs > 0; ofs >>= 1) mx = fmax(mx, __shfl_xor(mx, ofs));
  float ex = lead ? (expf((float)(v0 - mx)) + expf((float)(v1 - mx))) : 0.f;
  for (int ofs = 32; ofs > 0; ofs >>= 1) ex += __shfl_xor(ex, ofs);
  float l = logf(ex);
  if (lead) {
    float2 o = make_float2((float)(v0 - mx) - l, (float)(v1 - mx) - l);
    *(float2*)(out + (size_t)d * DO + 2 * p) = o;
  }
}

// ---------------- launch ----------------
extern "C" void kernel_launch(void* const* d_in, const int* in_sizes, int n_in,
                              void* d_out, int out_size, void* d_ws, size_t ws_size,
                              hipStream_t stream) {
  (void)in_sizes; (void)n_in; (void)out_size; (void)ws_size;
  const float* x  = (const float*)d_in[0];
  const int*   ei = (const int*)d_in[1];
  const float* w0 = (const float*)d_in[2];
  const float* b0 = (const float*)d_in[3];
  const float* w1 = (const float*)d_in[4];
  const float* b1 = (const float*)d_in[5];
  const float* w2 = (const float*)d_in[6];
  const float* b2 = (const float*)d_in[7];
  float* out = (float*)d_out;

  // ---- workspace carve-up (~17 MB)
  char* wsb = (char*)d_ws;
  double*   mean_d = (double*)wsb;                    // [512] col sums->means
  double*   wsum_d = (double*)(wsb + 4096);           // [3]            pad->4224
  uint32_t* deg_e  = (uint32_t*)(wsb + 4224);         // [NN] edge-only degree
  uint32_t* cursor = (uint32_t*)(wsb + 204224);       // [NN] fill cursors
  // bytes [0, 404224) are zeroed each call
  size_t cur = 404480;
  uint32_t* rowptr = (uint32_t*)(wsb + cur); cur += 200064;   // [NN+1] (pre-base)
  double*   dinv_d = (double*)(wsb + cur);  cur += 400000;
  cur = (cur + 255) & ~255ull;
  uint32_t* bsum = (uint32_t*)(wsb + cur); cur += 1024;       // [NBLK]
  uint32_t* base = (uint32_t*)(wsb + cur); cur += 1024;       // [NBLK]
  int*    csr_src = (int*)(wsb + cur);    cur += (size_t)NE * 4;   // 2.4 MB
  cur = (cur + 255) & ~255ull;
  uint32_t* FR0 = (uint32_t*)(wsb + cur); cur += 8 * 8 * 64 * 16;  // 64 KB
  uint32_t* FR1 = (uint32_t*)(wsb + cur); cur += 2 * 8 * 64 * 16;  // 16 KB
  uint32_t* FR2 = (uint32_t*)(wsb + cur); cur += 2 * 3 * 64 * 16;  // 6 KB
  int8_t* S1  = (int8_t*)(wsb + cur); cur += (size_t)MTOT;         // 6.4 MB
  cur = (cur + 255) & ~255ull;
  int8_t* H8 = (int8_t*)(wsb + cur); cur += (size_t)MTOT;          // 6.4 MB

  // fold_in(key(42), i): key=(0,42); folded = threefry(key, (0,i)) full output
  uint32_t fkA0, fkA1, fkB0, fkB1;
  threefry2x32(0u, 42u, 0u, 0u, &fkA0, &fkA1);
  threefry2x32(0u, 42u, 0u, 1u, &fkB0, &fkB1);

  // zero mean/wsum/deg/cursor (ws is poisoned 0xAA before every call)
  hipMemsetAsync(wsb, 0, 404224, stream);

  // MEGA-1: colsum || deg_edges || wfuse  (2630 blocks)
  prologue_fused<<<200 + DEGB + 86, 256, 0, stream>>>(
      x, mean_d, ei, deg_e, w0, w1, w2, FR0, FR1, FR2, wsum_d);
  // MEGA-2: scan_blocks || mean_finalize  (198 blocks)
  scan_mean<<<NBLK + 2, 256, 0, stream>>>(deg_e, rowptr, bsum, dinv_d, mean_d);
  scan_bsum<<<1, 256, 0, stream>>>(bsum, base);
  csr_fill<<<DEGB, 256, 0, stream>>>(ei, rowptr, base, cursor, csr_src);

  const int gemm_blocks = (NN / 16 + 3) / 4;            // 782 (4 waves x 16 rows)
  const int node_blocks = (NN * 64) / 256 + 1;          // 12501 waves >= NN
  const size_t sh0 = 8 * 8 * 64 * 16;                   // 64 KB
  const size_t sh1 = 2 * 8 * 64 * 16;                   // 16 KB
  const size_t sh2 = 2 * 3 * 64 * 16;                   // 6 KB

  // layer 0: K=512 -> DH, bn_sign fused (H = h/2 exact; x2 folded into cnt)
  gemm0_fused<<<gemm_blocks, 256, sh0, stream>>>(x, mean_d, FR0, H8);
  gather128<<<node_blocks, 256, 0, stream>>>(rowptr, base, csr_src, dinv_d, H8,
                                             b0, S1, wsum_d + 0,
                                             (double)(DI * DH / 2), fkA0, fkA1);

  // layer 1: K=128 -> DH
  gemm_mfma<2, 8, DH, 0><<<gemm_blocks, 256, sh1, stream>>>(S1, FR1, H8);
  gather128<<<node_blocks, 256, 0, stream>>>(rowptr, base, csr_src, dinv_d, H8,
                                             b1, S1, wsum_d + 1,
                                             (double)(DH * DH), fkB0, fkB1);

  // layer 2: K=128 -> DO, fused log_softmax
  gemm_mfma<2, 3, DO, 0><<<gemm_blocks, 256, sh2, stream>>>(S1, FR2, H8);
  gather40_lsm<<<node_blocks, 256, 0, stream>>>(rowptr, base, csr_src, dinv_d,
                                                H8, b2, wsum_d + 2, out);
}

// Round 7
// 385.667 us; speedup vs baseline: 1.0409x; 1.0064x over previous
//
#include <hip/hip_runtime.h>
#include <stdint.h>
#include <stddef.h>

#define NN 50000
#define NE 600000
#define DI 512
#define DH 128
#define DO 40
#define MTOT (NN * DH)   // 6,400,000
#define NBLK ((NN + 255) / 256)   // 196 scan blocks
#define DEGB ((NE + 255) / 256)   // 2344 deg blocks
#define CSB 400                   // colsum blocks (1 chain/thread)

using int4v = __attribute__((ext_vector_type(4))) int;

// ---------------- threefry2x32 (exact JAX semantics) ----------------
__host__ __device__ inline uint32_t rotl32(uint32_t v, int d) {
  return (v << d) | (v >> (32 - d));
}

__host__ __device__ inline void threefry2x32(uint32_t k0, uint32_t k1,
                                             uint32_t c0, uint32_t c1,
                                             uint32_t* o0, uint32_t* o1) {
  uint32_t ks0 = k0, ks1 = k1, ks2 = k0 ^ k1 ^ 0x1BD11BDAu;
  uint32_t x0 = c0 + ks0, x1 = c1 + ks1;
  const int R0[4] = {13, 15, 26, 6};
  const int R1[4] = {17, 29, 16, 24};
#define TF_R4(R) { x0 += x1; x1 = rotl32(x1, R[0]); x1 ^= x0; \
                   x0 += x1; x1 = rotl32(x1, R[1]); x1 ^= x0; \
                   x0 += x1; x1 = rotl32(x1, R[2]); x1 ^= x0; \
                   x0 += x1; x1 = rotl32(x1, R[3]); x1 ^= x0; }
  TF_R4(R0); x0 += ks1; x1 += ks2 + 1u;
  TF_R4(R1); x0 += ks2; x1 += ks0 + 2u;
  TF_R4(R0); x0 += ks0; x1 += ks1 + 3u;
  TF_R4(R1); x0 += ks1; x1 += ks2 + 4u;
  TF_R4(R0); x0 += ks2; x1 += ks0 + 5u;
#undef TF_R4
  *o0 = x0; *o1 = x1;
}

// ---- BN column sums — chains (grp 0..199, col 0..511), 1 chain/thread -----
// NUMERICALLY LIVE: per-chain f64 add ORDER unchanged (rows ascending, same
// sequence as all prior passing rounds). Chain->thread packing is free; the
// cross-block f64 atomic order was already nondeterministic.
// Named scalars + asm barrier FORCE 10 outstanding loads (r5: compiler sank
// the array version back to serial load->add at VGPR_Count=24).
__device__ inline void colsum_body(const float* __restrict__ x,
                                   double* __restrict__ colsum, int blk) {
  const int t = threadIdx.x;
  const int grp = blk >> 1;                    // 0..199
  const int col = ((blk & 1) << 8) + t;        // 0..511
  const float* xp = x + (size_t)grp * 250 * DI + col;
  double s = 0.0;
  for (int i = 0; i < 25; ++i) {
    double d0 = (double)xp[0 * DI];
    double d1 = (double)xp[1 * DI];
    double d2 = (double)xp[2 * DI];
    double d3 = (double)xp[3 * DI];
    double d4 = (double)xp[4 * DI];
    double d5 = (double)xp[5 * DI];
    double d6 = (double)xp[6 * DI];
    double d7 = (double)xp[7 * DI];
    double d8 = (double)xp[8 * DI];
    double d9 = (double)xp[9 * DI];
    asm volatile("" ::: "memory");             // pin loads before the chain
    s += d0; s += d1; s += d2; s += d3; s += d4;
    s += d5; s += d6; s += d7; s += d8; s += d9;   // ascending row order
    xp += 10 * DI;
  }
  unsafeAtomicAdd(&colsum[col], s);
}

// ---- fused weight prep body: MFMA B-fragments from float w + sum|w| -------
__device__ inline void wfuse_body(const float* __restrict__ w,
                                  uint32_t* __restrict__ frag,
                                  double* __restrict__ slot,
                                  int K, int C, int NT, int blk,
                                  double* red) {
  int steps = K >> 6;
  int total = steps * NT * 64 * 4;
  int idx = blk * 256 + threadIdx.x;
  double a = 0.0;
  if (idx < total) {
    int dw = idx & 3;
    int lane = (idx >> 2) & 63;
    int rest = idx >> 8;
    int t = rest % NT;
    int s = rest / NT;
    int n = t * 16 + (lane & 15);
    int kbase = s * 64 + (lane >> 4) * 16 + dw * 4;
    uint32_t v = 0;
    if (n < C) {
#pragma unroll
      for (int j = 0; j < 4; ++j) {
        float wv = w[(size_t)(kbase + j) * C + n];
        uint32_t sg = (uint8_t)(int8_t)((wv > 0.f) ? 1 : ((wv < 0.f) ? -1 : 0));
        v |= sg << (8 * j);
        a += (double)fabsf(wv);
      }
    }
    frag[idx] = v;
  }
  red[threadIdx.x] = a;
  __syncthreads();
  for (int ofs = 128; ofs > 0; ofs >>= 1) {
    if (threadIdx.x < ofs) red[threadIdx.x] += red[threadIdx.x + ofs];
    __syncthreads();
  }
  if (threadIdx.x == 0) unsafeAtomicAdd(slot, red[0]);
}

// ---- MEGA-1: colsum [0,400) || deg_edges [400,2744) || wfuse [2744,2830) ---
__global__ void prologue_fused(const float* __restrict__ x,
                               double* __restrict__ colsum,
                               const int* __restrict__ ei,
                               uint32_t* __restrict__ deg,
                               const float* __restrict__ w0,
                               const float* __restrict__ w1,
                               const float* __restrict__ w2,
                               uint32_t* __restrict__ f0,
                               uint32_t* __restrict__ f1,
                               uint32_t* __restrict__ f2,
                               double* __restrict__ slots) {
  __shared__ double red[256];
  int b = blockIdx.x;
  if (b < CSB) {
    colsum_body(x, colsum, b);
  } else if (b < CSB + DEGB) {
    int e = (b - CSB) * 256 + threadIdx.x;
    if (e < NE) atomicAdd(&deg[ei[e]], 1u);   // ei[0:E] = destinations
  } else {
    int wb = b - (CSB + DEGB);
    if (wb < 64)       wfuse_body(w0, f0, slots + 0, DI, DH, 8, wb,      red);
    else if (wb < 80)  wfuse_body(w1, f1, slots + 1, DH, DH, 8, wb - 64, red);
    else               wfuse_body(w2, f2, slots + 2, DH, DO, 3, wb - 80, red);
  }
}

// ---- MEGA-2: scan_blocks [0,196) || mean_finalize [196,198) ----------------
__global__ void scan_mean(const uint32_t* __restrict__ deg,
                          uint32_t* __restrict__ rowptr,
                          uint32_t* __restrict__ bsum,
                          double* __restrict__ dinv,
                          double* __restrict__ colsum) {
  __shared__ uint32_t bs[256];
  int b = blockIdx.x;
  int t = threadIdx.x;
  if (b < NBLK) {
    int i = b * 256 + t;
    uint32_t v = (i < NN) ? deg[i] : 0u;
    if (i < NN) dinv[i] = 1.0 / sqrt((double)(v + 1u));   // +1 self-loop
    bs[t] = v;
    __syncthreads();
    for (int ofs = 1; ofs < 256; ofs <<= 1) {
      uint32_t add = (t >= ofs) ? bs[t - ofs] : 0u;
      __syncthreads();
      bs[t] += add;
      __syncthreads();
    }
    if (i < NN) rowptr[i] = bs[t] - v;     // exclusive within block (pre-base)
    if (t == 255) bsum[b] = bs[255];
  } else {
    int c = (b - NBLK) * 256 + t;
    if (c < DI) colsum[c] = colsum[c] / (double)NN;
  }
}

__global__ void scan_bsum(const uint32_t* __restrict__ bsum,
                          uint32_t* __restrict__ base) {
  __shared__ uint32_t bs[256];
  int t = threadIdx.x;
  uint32_t v = (t < NBLK) ? bsum[t] : 0u;
  bs[t] = v;
  __syncthreads();
  for (int ofs = 1; ofs < 256; ofs <<= 1) {
    uint32_t add = (t >= ofs) ? bs[t - ofs] : 0u;
    __syncthreads();
    bs[t] += add;
    __syncthreads();
  }
  if (t < NBLK) base[t] = bs[t] - v;
}

// csr_fill with scan_addbase folded in: global pos = rowptr[dst]+base[dst>>8]
__global__ void csr_fill(const int* __restrict__ ei,
                         const uint32_t* __restrict__ rowptr,
                         const uint32_t* __restrict__ base,
                         uint32_t* __restrict__ cursor,
                         int* __restrict__ csr_src) {
  int e = blockIdx.x * blockDim.x + threadIdx.x;
  if (e >= NE) return;
  int dst = ei[e], src = ei[NE + e];
  uint32_t pos = rowptr[dst] + base[dst >> 8] + atomicAdd(&cursor[dst], 1u);
  csr_src[pos] = src;
}

// ---------------- ternary GEMM via MFMA i8 16x16x64 -----------------------
template <int STEPS, int NT, int C, int SHIFT>
__global__ void gemm_mfma(const int8_t* __restrict__ S,
                          const uint32_t* __restrict__ frag,
                          int8_t* __restrict__ H) {
  extern __shared__ uint4 lb[];
  const int tot = STEPS * NT * 64;
  const uint4* fg = (const uint4*)frag;
  for (int i = threadIdx.x; i < tot; i += 256) lb[i] = fg[i];
  __syncthreads();
  const int lane = threadIdx.x & 63;
  const int wv = threadIdx.x >> 6;
  const int r0 = (blockIdx.x * 4 + wv) * 16;
  if (r0 >= NN) return;                 // NN % 16 == 0
  const int m = lane & 15, q = lane >> 4;
  const int K = STEPS * 64;
  const int8_t* sp = S + (size_t)(r0 + m) * K + q * 16;
  int4v acc[NT];
#pragma unroll
  for (int t = 0; t < NT; ++t) acc[t] = (int4v){0, 0, 0, 0};
#pragma unroll
  for (int s = 0; s < STEPS; ++s) {
    int4v a = *(const int4v*)(sp + (size_t)s * 64);
#pragma unroll
    for (int t = 0; t < NT; ++t) {
      int4v b = *(const int4v*)&lb[(s * NT + t) * 64 + lane];
      acc[t] = __builtin_amdgcn_mfma_i32_16x16x64_i8(a, b, acc[t], 0, 0, 0);
    }
  }
  int8_t* hp = H + (size_t)r0 * C;
#pragma unroll
  for (int t = 0; t < NT; ++t) {
    int n = t * 16 + m;
    if (n < C) {
#pragma unroll
      for (int r = 0; r < 4; ++r)
        hp[(size_t)(q * 4 + r) * C + n] = (int8_t)(acc[t][r] >> SHIFT);
    }
  }
}

// ---- layer-0 GEMM with bn_sign fused into the A-fragment load -------------
__global__ void gemm0_fused(const float* __restrict__ x,
                            const double* __restrict__ mean,
                            const uint32_t* __restrict__ frag,
                            int8_t* __restrict__ H) {
  extern __shared__ uint4 lb[];
  const int tot = 8 * 8 * 64;                       // 4096 uint4 = 64 KB
  const uint4* fg = (const uint4*)frag;
  for (int i = threadIdx.x; i < tot; i += 256) lb[i] = fg[i];
  __syncthreads();
  const int lane = threadIdx.x & 63;
  const int wv = threadIdx.x >> 6;
  const int r0 = (blockIdx.x * 4 + wv) * 16;
  if (r0 >= NN) return;
  const int m = lane & 15, q = lane >> 4;
  const float* xp = x + (size_t)(r0 + m) * DI + q * 16;
  const double* mp0 = mean + q * 16;
  int4v acc[8];
#pragma unroll
  for (int t = 0; t < 8; ++t) acc[t] = (int4v){0, 0, 0, 0};
#pragma unroll
  for (int s = 0; s < 8; ++s) {
    const float* xs = xp + s * 64;
    const double* mp = mp0 + s * 64;
    int4v a;
#pragma unroll
    for (int w4 = 0; w4 < 4; ++w4) {
      float4 f = *(const float4*)(xs + 4 * w4);
      double v0 = (double)f.x - mp[4 * w4 + 0];
      double v1 = (double)f.y - mp[4 * w4 + 1];
      double v2 = (double)f.z - mp[4 * w4 + 2];
      double v3 = (double)f.w - mp[4 * w4 + 3];
      uint32_t o = 0;
      o |= (uint8_t)(int8_t)((v0 > 0.0) ? 1 : ((v0 < 0.0) ? -1 : 0));
      o |= ((uint32_t)(uint8_t)(int8_t)((v1 > 0.0) ? 1 : ((v1 < 0.0) ? -1 : 0))) << 8;
      o |= ((uint32_t)(uint8_t)(int8_t)((v2 > 0.0) ? 1 : ((v2 < 0.0) ? -1 : 0))) << 16;
      o |= ((uint32_t)(uint8_t)(int8_t)((v3 > 0.0) ? 1 : ((v3 < 0.0) ? -1 : 0))) << 24;
      a[w4] = (int)o;
    }
#pragma unroll
    for (int t = 0; t < 8; ++t) {
      int4v b = *(const int4v*)&lb[(s * 8 + t) * 64 + lane];
      acc[t] = __builtin_amdgcn_mfma_i32_16x16x64_i8(a, b, acc[t], 0, 0, 0);
    }
  }
  int8_t* hp = H + (size_t)r0 * DH;
#pragma unroll
  for (int t = 0; t < 8; ++t) {
    int n = t * 16 + m;
#pragma unroll
    for (int r = 0; r < 4; ++r)
      hp[(size_t)(q * 4 + r) * DH + n] = (int8_t)(acc[t][r] >> 1);
  }
}

// ---- gather (C=128): ORDER-PRESERVING, 1-deep prefetch, base folded in ----
__global__ void gather128(const uint32_t* __restrict__ rowptr,
                          const uint32_t* __restrict__ base,
                          const int* __restrict__ csr_src,
                          const double* __restrict__ dinv,
                          const int8_t* __restrict__ H,
                          const float* __restrict__ b,
                          int8_t* __restrict__ Sout,
                          const double* __restrict__ wsum, double cnt,
                          uint32_t fk0, uint32_t fk1) {
  int d = (int)(((size_t)blockIdx.x * blockDim.x + threadIdx.x) >> 6);
  int lane = threadIdx.x & 63;
  if (d >= NN) return;
  const int g = lane >> 5, p = lane & 31;
  double a0 = 0.0, a1 = 0.0, a2 = 0.0, a3 = 0.0;
  const uint32_t e0 = rowptr[d] + base[d >> 8];
  const uint32_t e1 = (d + 1 < NN) ? (rowptr[d + 1] + base[(d + 1) >> 8]) : NE;
  const int L = (int)(e1 - e0) + 1;               // + self-loop (edge 0)
  for (int c0 = 0; c0 < L; c0 += 64) {
    const int n = min(64, L - c0);
    const int my = c0 + lane;
    int sidx = d;
    if (my > 0 && my < L) sidx = csr_src[e0 + my - 1];
    double wv = dinv[sidx];                       // sidx=d is valid fallback
    int t = 0;
    {
      int sA = 0, sB = 0; double wA = 0.0, wB = 0.0;
      uint32_t hA = 0, hB = 0;
      if (4 <= n) {                               // wave-uniform
        sA = __shfl(sidx, g);      wA = __shfl(wv, g);
        sB = __shfl(sidx, 2 + g);  wB = __shfl(wv, 2 + g);
        hA = *(const uint32_t*)(H + (size_t)sA * DH + 4 * p);
        hB = *(const uint32_t*)(H + (size_t)sB * DH + 4 * p);
      }
      for (; t + 4 <= n; t += 4) {
        const uint32_t cA = hA, cB = hB;
        const double vA = wA, vB = wB;
        if (t + 8 <= n) {                         // prefetch next pair
          sA = __shfl(sidx, t + 4 + g);  wA = __shfl(wv, t + 4 + g);
          sB = __shfl(sidx, t + 6 + g);  wB = __shfl(wv, t + 6 + g);
          hA = *(const uint32_t*)(H + (size_t)sA * DH + 4 * p);
          hB = *(const uint32_t*)(H + (size_t)sB * DH + 4 * p);
        }
        a0 += vA * (double)(int8_t)(cA);
        a1 += vA * (double)(int8_t)(cA >> 8);
        a2 += vA * (double)(int8_t)(cA >> 16);
        a3 += vA * (double)(int8_t)(cA >> 24);
        a0 += vB * (double)(int8_t)(cB);
        a1 += vB * (double)(int8_t)(cB >> 8);
        a2 += vB * (double)(int8_t)(cB >> 16);
        a3 += vB * (double)(int8_t)(cB >> 24);
      }
    }
    for (; t < n; t += 2) {                       // non-divergent tail
      const int j = t + g;
      const bool on = (j < n);
      const int jc = on ? j : 0;
      int s = __shfl(sidx, jc);
      double w = __shfl(wv, jc);
      w = on ? w : 0.0;
      uint32_t hv = *(const uint32_t*)(H + (size_t)s * DH + 4 * p);
      a0 += w * (double)(int8_t)(hv);
      a1 += w * (double)(int8_t)(hv >> 8);
      a2 += w * (double)(int8_t)(hv >> 16);
      a3 += w * (double)(int8_t)(hv >> 24);
    }
  }
  a0 += __shfl_xor(a0, 32);
  a1 += __shfl_xor(a1, 32);
  a2 += __shfl_xor(a2, 32);
  a3 += __shfl_xor(a3, 32);
  double sc = (wsum[0] / cnt) * dinv[d];
  int ch = 4 * p + 2 * g;
  int j0 = d * DH + ch;
  double va = sc * ((g == 0) ? a0 : a2) + (double)b[ch];
  double vb = sc * ((g == 0) ? a1 : a3) + (double)b[ch + 1];
  int s0 = (va > 0.0) ? 1 : ((va < 0.0) ? -1 : 0);
  int s1 = (vb > 0.0) ? 1 : ((vb < 0.0) ? -1 : 0);
  uint32_t r0, r1, bits0, bits1;
  threefry2x32(fk0, fk1, 0u, (uint32_t)j0, &r0, &r1);
  bits0 = r0 ^ r1;
  threefry2x32(fk0, fk1, 0u, (uint32_t)(j0 + 1), &r0, &r1);
  bits1 = r0 ^ r1;
  float u0 = __uint_as_float((bits0 >> 9) | 0x3f800000u) - 1.0f;
  float u1 = __uint_as_float((bits1 >> 9) | 0x3f800000u) - 1.0f;
  uint8_t o0 = (u0 < 0.5f) ? (uint8_t)(int8_t)s0 : (uint8_t)0;
  uint8_t o1 = (u1 < 0.5f) ? (uint8_t)(int8_t)s1 : (uint8_t)0;
  *(uint16_t*)(Sout + j0) = (uint16_t)(o0 | ((uint16_t)o1 << 8));
}

// ---- gather (C=40): ORDER-PRESERVING, base folded in, fused log_softmax ---
__global__ void gather40_lsm(const uint32_t* __restrict__ rowptr,
                             const uint32_t* __restrict__ base,
                             const int* __restrict__ csr_src,
                             const double* __restrict__ dinv,
                             const int8_t* __restrict__ H,
                             const float* __restrict__ b2,
                             const double* __restrict__ wsum,
                             float* __restrict__ out) {
  int d = (int)(((size_t)blockIdx.x * blockDim.x + threadIdx.x) >> 6);
  int lane = threadIdx.x & 63;
  if (d >= NN) return;
  const int g = lane >> 5, p = lane & 31;
  const bool act = (p < 20);
  double a0 = 0.0, a1 = 0.0;
  const uint32_t e0 = rowptr[d] + base[d >> 8];
  const uint32_t e1 = (d + 1 < NN) ? (rowptr[d + 1] + base[(d + 1) >> 8]) : NE;
  const int L = (int)(e1 - e0) + 1;
  for (int c0 = 0; c0 < L; c0 += 64) {
    const int n = min(64, L - c0);
    const int my = c0 + lane;
    int sidx = d;
    if (my > 0 && my < L) sidx = csr_src[e0 + my - 1];
    double wv = dinv[sidx];
    int t = 0;
    {
      int sA = 0, sB = 0; double wA = 0.0, wB = 0.0;
      uint16_t hA = 0, hB = 0;
      if (4 <= n) {
        sA = __shfl(sidx, g);      wA = __shfl(wv, g);
        sB = __shfl(sidx, 2 + g);  wB = __shfl(wv, 2 + g);
        if (act) {
          hA = *(const uint16_t*)(H + (size_t)sA * DO + 2 * p);
          hB = *(const uint16_t*)(H + (size_t)sB * DO + 2 * p);
        }
      }
      for (; t + 4 <= n; t += 4) {
        const uint16_t cA = hA, cB = hB;
        const double vA = wA, vB = wB;
        if (t + 8 <= n) {
          sA = __shfl(sidx, t + 4 + g);  wA = __shfl(wv, t + 4 + g);
          sB = __shfl(sidx, t + 6 + g);  wB = __shfl(wv, t + 6 + g);
          if (act) {
            hA = *(const uint16_t*)(H + (size_t)sA * DO + 2 * p);
            hB = *(const uint16_t*)(H + (size_t)sB * DO + 2 * p);
          }
        }
        if (act) {
          a0 += vA * (double)(int8_t)(cA);
          a1 += vA * (double)(int8_t)(cA >> 8);
          a0 += vB * (double)(int8_t)(cB);
          a1 += vB * (double)(int8_t)(cB >> 8);
        }
      }
    }
    for (; t < n; t += 2) {
      const int j = t + g;
      const bool on = (j < n);
      const int jc = on ? j : 0;
      int s = __shfl(sidx, jc);
      double w = __shfl(wv, jc);
      w = on ? w : 0.0;
      if (act) {
        uint16_t hv = *(const uint16_t*)(H + (size_t)s * DO + 2 * p);
        a0 += w * (double)(int8_t)(hv);
        a1 += w * (double)(int8_t)(hv >> 8);
      }
    }
  }
  a0 += __shfl_xor(a0, 32);
  a1 += __shfl_xor(a1, 32);
  double sc = (wsum[0] / (double)(DH * DO)) * dinv[d];
  const bool lead = (g == 0) && act;
  double v0 = 0.0, v1 = 0.0;
  if (act) {
    v0 = sc * a0 + (double)b2[2 * p];
    v1 = sc * a1 + (double)b2[2 * p + 1];
  }
  double mx = lead ? fmax(v0, v1) : -1.0e300;
  for (int ofs = 32; ofs > 0; ofs >>= 1) mx = fmax(mx, __shfl_xor(mx, ofs));
  float ex = lead ? (expf((float)(v0 - mx)) + expf((float)(v1 - mx))) : 0.f;
  for (int ofs = 32; ofs > 0; ofs >>= 1) ex += __shfl_xor(ex, ofs);
  float l = logf(ex);
  if (lead) {
    float2 o = make_float2((float)(v0 - mx) - l, (float)(v1 - mx) - l);
    *(float2*)(out + (size_t)d * DO + 2 * p) = o;
  }
}

// ---------------- launch ----------------
extern "C" void kernel_launch(void* const* d_in, const int* in_sizes, int n_in,
                              void* d_out, int out_size, void* d_ws, size_t ws_size,
                              hipStream_t stream) {
  (void)in_sizes; (void)n_in; (void)out_size; (void)ws_size;
  const float* x  = (const float*)d_in[0];
  const int*   ei = (const int*)d_in[1];
  const float* w0 = (const float*)d_in[2];
  const float* b0 = (const float*)d_in[3];
  const float* w1 = (const float*)d_in[4];
  const float* b1 = (const float*)d_in[5];
  const float* w2 = (const float*)d_in[6];
  const float* b2 = (const float*)d_in[7];
  float* out = (float*)d_out;

  // ---- workspace carve-up (~17 MB)
  char* wsb = (char*)d_ws;
  double*   mean_d = (double*)wsb;                    // [512] col sums->means
  double*   wsum_d = (double*)(wsb + 4096);           // [3]            pad->4224
  uint32_t* deg_e  = (uint32_t*)(wsb + 4224);         // [NN] edge-only degree
  uint32_t* cursor = (uint32_t*)(wsb + 204224);       // [NN] fill cursors
  // bytes [0, 404224) are zeroed each call
  size_t cur = 404480;
  uint32_t* rowptr = (uint32_t*)(wsb + cur); cur += 200064;   // [NN+1] (pre-base)
  double*   dinv_d = (double*)(wsb + cur);  cur += 400000;
  cur = (cur + 255) & ~255ull;
  uint32_t* bsum = (uint32_t*)(wsb + cur); cur += 1024;       // [NBLK]
  uint32_t* base = (uint32_t*)(wsb + cur); cur += 1024;       // [NBLK]
  int*    csr_src = (int*)(wsb + cur);    cur += (size_t)NE * 4;   // 2.4 MB
  cur = (cur + 255) & ~255ull;
  uint32_t* FR0 = (uint32_t*)(wsb + cur); cur += 8 * 8 * 64 * 16;  // 64 KB
  uint32_t* FR1 = (uint32_t*)(wsb + cur); cur += 2 * 8 * 64 * 16;  // 16 KB
  uint32_t* FR2 = (uint32_t*)(wsb + cur); cur += 2 * 3 * 64 * 16;  // 6 KB
  int8_t* S1  = (int8_t*)(wsb + cur); cur += (size_t)MTOT;         // 6.4 MB
  cur = (cur + 255) & ~255ull;
  int8_t* H8 = (int8_t*)(wsb + cur); cur += (size_t)MTOT;          // 6.4 MB

  // fold_in(key(42), i): key=(0,42); folded = threefry(key, (0,i)) full output
  uint32_t fkA0, fkA1, fkB0, fkB1;
  threefry2x32(0u, 42u, 0u, 0u, &fkA0, &fkA1);
  threefry2x32(0u, 42u, 0u, 1u, &fkB0, &fkB1);

  // zero mean/wsum/deg/cursor (ws is poisoned 0xAA before every call)
  hipMemsetAsync(wsb, 0, 404224, stream);

  // MEGA-1: colsum || deg_edges || wfuse  (2830 blocks)
  prologue_fused<<<CSB + DEGB + 86, 256, 0, stream>>>(
      x, mean_d, ei, deg_e, w0, w1, w2, FR0, FR1, FR2, wsum_d);
  // MEGA-2: scan_blocks || mean_finalize  (198 blocks)
  scan_mean<<<NBLK + 2, 256, 0, stream>>>(deg_e, rowptr, bsum, dinv_d, mean_d);
  scan_bsum<<<1, 256, 0, stream>>>(bsum, base);
  csr_fill<<<DEGB, 256, 0, stream>>>(ei, rowptr, base, cursor, csr_src);

  const int gemm_blocks = (NN / 16 + 3) / 4;            // 782 (4 waves x 16 rows)
  const int node_blocks = (NN * 64) / 256 + 1;          // 12501 waves >= NN
  const size_t sh0 = 8 * 8 * 64 * 16;                   // 64 KB
  const size_t sh1 = 2 * 8 * 64 * 16;                   // 16 KB
  const size_t sh2 = 2 * 3 * 64 * 16;                   // 6 KB

  // layer 0: K=512 -> DH, bn_sign fused (H = h/2 exact; x2 folded into cnt)
  gemm0_fused<<<gemm_blocks, 256, sh0, stream>>>(x, mean_d, FR0, H8);
  gather128<<<node_blocks, 256, 0, stream>>>(rowptr, base, csr_src, dinv_d, H8,
                                             b0, S1, wsum_d + 0,
                                             (double)(DI * DH / 2), fkA0, fkA1);

  // layer 1: K=128 -> DH
  gemm_mfma<2, 8, DH, 0><<<gemm_blocks, 256, sh1, stream>>>(S1, FR1, H8);
  gather128<<<node_blocks, 256, 0, stream>>>(rowptr, base, csr_src, dinv_d, H8,
                                             b1, S1, wsum_d + 1,
                                             (double)(DH * DH), fkB0, fkB1);

  // layer 2: K=128 -> DO, fused log_softmax
  gemm_mfma<2, 3, DO, 0><<<gemm_blocks, 256, sh2, stream>>>(S1, FR2, H8);
  gather40_lsm<<<node_blocks, 256, 0, stream>>>(rowptr, base, csr_src, dinv_d,
                                                H8, b2, wsum_d + 2, out);
}

// Round 8
// 372.521 us; speedup vs baseline: 1.0776x; 1.0353x over previous
//
#include <hip/hip_runtime.h>
#include <stdint.h>
#include <stddef.h>

#define NN 50000
#define NE 600000
#define DI 512
#define DH 128
#define DO 40
#define MTOT (NN * DH)   // 6,400,000
#define NBLK ((NN + 255) / 256)   // 196 scan blocks
#define DEGB ((NE + 255) / 256)   // 2344 deg blocks
#define CSB 400                   // colsum blocks (1 chain/thread)
#define GEMMB ((NN / 16 + 3) / 4) // 782 gemm blocks

using int4v = __attribute__((ext_vector_type(4))) int;

// ---------------- threefry2x32 (exact JAX semantics) ----------------
__host__ __device__ inline uint32_t rotl32(uint32_t v, int d) {
  return (v << d) | (v >> (32 - d));
}

__host__ __device__ inline void threefry2x32(uint32_t k0, uint32_t k1,
                                             uint32_t c0, uint32_t c1,
                                             uint32_t* o0, uint32_t* o1) {
  uint32_t ks0 = k0, ks1 = k1, ks2 = k0 ^ k1 ^ 0x1BD11BDAu;
  uint32_t x0 = c0 + ks0, x1 = c1 + ks1;
  const int R0[4] = {13, 15, 26, 6};
  const int R1[4] = {17, 29, 16, 24};
#define TF_R4(R) { x0 += x1; x1 = rotl32(x1, R[0]); x1 ^= x0; \
                   x0 += x1; x1 = rotl32(x1, R[1]); x1 ^= x0; \
                   x0 += x1; x1 = rotl32(x1, R[2]); x1 ^= x0; \
                   x0 += x1; x1 = rotl32(x1, R[3]); x1 ^= x0; }
  TF_R4(R0); x0 += ks1; x1 += ks2 + 1u;
  TF_R4(R1); x0 += ks2; x1 += ks0 + 2u;
  TF_R4(R0); x0 += ks0; x1 += ks1 + 3u;
  TF_R4(R1); x0 += ks1; x1 += ks2 + 4u;
  TF_R4(R0); x0 += ks2; x1 += ks0 + 5u;
#undef TF_R4
  *o0 = x0; *o1 = x1;
}

// ---- BN column sums — chains (grp 0..199, col 0..511), 1 chain/thread -----
// NUMERICALLY LIVE: per-chain f64 add ORDER unchanged (rows ascending).
// r7 lesson: "memory" clobber does NOT order register-only adds -> compiler
// interleaved load/add (serial, 590cyc/row, VGPR=16). Fix: the 25 row values
// are ASM OPERANDS -> all must be live in regs at that point -> 25 loads
// issue back-to-back (one waitcnt), then the ordered f64 chain.
__device__ inline void colsum_body(const float* __restrict__ x,
                                   double* __restrict__ colsum, int blk) {
  const int t = threadIdx.x;
  const int grp = blk >> 1;                    // 0..199
  const int col = ((blk & 1) << 8) + t;        // 0..511
  const float* xp = x + (size_t)grp * 250 * DI + col;
  double s = 0.0;
  for (int i = 0; i < 10; ++i) {
    float f0  = xp[0 * DI],  f1  = xp[1 * DI],  f2  = xp[2 * DI];
    float f3  = xp[3 * DI],  f4  = xp[4 * DI],  f5  = xp[5 * DI];
    float f6  = xp[6 * DI],  f7  = xp[7 * DI],  f8  = xp[8 * DI];
    float f9  = xp[9 * DI],  f10 = xp[10 * DI], f11 = xp[11 * DI];
    float f12 = xp[12 * DI], f13 = xp[13 * DI], f14 = xp[14 * DI];
    float f15 = xp[15 * DI], f16 = xp[16 * DI], f17 = xp[17 * DI];
    float f18 = xp[18 * DI], f19 = xp[19 * DI], f20 = xp[20 * DI];
    float f21 = xp[21 * DI], f22 = xp[22 * DI], f23 = xp[23 * DI];
    float f24 = xp[24 * DI];
    asm volatile("" :: "v"(f0), "v"(f1), "v"(f2), "v"(f3), "v"(f4),
                       "v"(f5), "v"(f6), "v"(f7), "v"(f8), "v"(f9),
                       "v"(f10), "v"(f11), "v"(f12), "v"(f13), "v"(f14),
                       "v"(f15), "v"(f16), "v"(f17), "v"(f18), "v"(f19),
                       "v"(f20), "v"(f21), "v"(f22), "v"(f23), "v"(f24));
    s += (double)f0;  s += (double)f1;  s += (double)f2;  s += (double)f3;
    s += (double)f4;  s += (double)f5;  s += (double)f6;  s += (double)f7;
    s += (double)f8;  s += (double)f9;  s += (double)f10; s += (double)f11;
    s += (double)f12; s += (double)f13; s += (double)f14; s += (double)f15;
    s += (double)f16; s += (double)f17; s += (double)f18; s += (double)f19;
    s += (double)f20; s += (double)f21; s += (double)f22; s += (double)f23;
    s += (double)f24;                       // ascending row order, unchanged
    xp += 25 * DI;
  }
  unsafeAtomicAdd(&colsum[col], s);
}

// ---- fused weight prep body: MFMA B-fragments from float w + sum|w| -------
__device__ inline void wfuse_body(const float* __restrict__ w,
                                  uint32_t* __restrict__ frag,
                                  double* __restrict__ slot,
                                  int K, int C, int NT, int blk,
                                  double* red) {
  int steps = K >> 6;
  int total = steps * NT * 64 * 4;
  int idx = blk * 256 + threadIdx.x;
  double a = 0.0;
  if (idx < total) {
    int dw = idx & 3;
    int lane = (idx >> 2) & 63;
    int rest = idx >> 8;
    int t = rest % NT;
    int s = rest / NT;
    int n = t * 16 + (lane & 15);
    int kbase = s * 64 + (lane >> 4) * 16 + dw * 4;
    uint32_t v = 0;
    if (n < C) {
#pragma unroll
      for (int j = 0; j < 4; ++j) {
        float wv = w[(size_t)(kbase + j) * C + n];
        uint32_t sg = (uint8_t)(int8_t)((wv > 0.f) ? 1 : ((wv < 0.f) ? -1 : 0));
        v |= sg << (8 * j);
        a += (double)fabsf(wv);
      }
    }
    frag[idx] = v;
  }
  red[threadIdx.x] = a;
  __syncthreads();
  for (int ofs = 128; ofs > 0; ofs >>= 1) {
    if (threadIdx.x < ofs) red[threadIdx.x] += red[threadIdx.x + ofs];
    __syncthreads();
  }
  if (threadIdx.x == 0) unsafeAtomicAdd(slot, red[0]);
}

// ---- MEGA-1: colsum [0,400) || deg_edges [400,2744) || wfuse [2744,2830) ---
__global__ void prologue_fused(const float* __restrict__ x,
                               double* __restrict__ colsum,
                               const int* __restrict__ ei,
                               uint32_t* __restrict__ deg,
                               const float* __restrict__ w0,
                               const float* __restrict__ w1,
                               const float* __restrict__ w2,
                               uint32_t* __restrict__ f0,
                               uint32_t* __restrict__ f1,
                               uint32_t* __restrict__ f2,
                               double* __restrict__ slots) {
  __shared__ double red[256];
  int b = blockIdx.x;
  if (b < CSB) {
    colsum_body(x, colsum, b);
  } else if (b < CSB + DEGB) {
    int e = (b - CSB) * 256 + threadIdx.x;
    if (e < NE) atomicAdd(&deg[ei[e]], 1u);   // ei[0:E] = destinations
  } else {
    int wb = b - (CSB + DEGB);
    if (wb < 64)       wfuse_body(w0, f0, slots + 0, DI, DH, 8, wb,      red);
    else if (wb < 80)  wfuse_body(w1, f1, slots + 1, DH, DH, 8, wb - 64, red);
    else               wfuse_body(w2, f2, slots + 2, DH, DO, 3, wb - 80, red);
  }
}

// ---- MEGA-2: scan_blocks [0,196) || mean_finalize [196,198) ----------------
__global__ void scan_mean(const uint32_t* __restrict__ deg,
                          uint32_t* __restrict__ rowptr,
                          uint32_t* __restrict__ bsum,
                          double* __restrict__ dinv,
                          double* __restrict__ colsum) {
  __shared__ uint32_t bs[256];
  int b = blockIdx.x;
  int t = threadIdx.x;
  if (b < NBLK) {
    int i = b * 256 + t;
    uint32_t v = (i < NN) ? deg[i] : 0u;
    if (i < NN) dinv[i] = 1.0 / sqrt((double)(v + 1u));   // +1 self-loop
    bs[t] = v;
    __syncthreads();
    for (int ofs = 1; ofs < 256; ofs <<= 1) {
      uint32_t add = (t >= ofs) ? bs[t - ofs] : 0u;
      __syncthreads();
      bs[t] += add;
      __syncthreads();
    }
    if (i < NN) rowptr[i] = bs[t] - v;     // exclusive within block (pre-base)
    if (t == 255) bsum[b] = bs[255];
  } else {
    int c = (b - NBLK) * 256 + t;
    if (c < DI) colsum[c] = colsum[c] / (double)NN;
  }
}

__global__ void scan_bsum(const uint32_t* __restrict__ bsum,
                          uint32_t* __restrict__ base) {
  __shared__ uint32_t bs[256];
  int t = threadIdx.x;
  uint32_t v = (t < NBLK) ? bsum[t] : 0u;
  bs[t] = v;
  __syncthreads();
  for (int ofs = 1; ofs < 256; ofs <<= 1) {
    uint32_t add = (t >= ofs) ? bs[t - ofs] : 0u;
    __syncthreads();
    bs[t] += add;
    __syncthreads();
  }
  if (t < NBLK) base[t] = bs[t] - v;
}

// ---- MEGA-3: csr_fill [0,2344) || gemm0 [2344,3126) ------------------------
// Independent: csr_src is consumed only by the later gathers; gemm0 reads
// x/mean/FR0. csr atomics hide under gemm0's MFMA.
__global__ void csr_gemm0(const int* __restrict__ ei,
                          const uint32_t* __restrict__ rowptr,
                          const uint32_t* __restrict__ base,
                          uint32_t* __restrict__ cursor,
                          int* __restrict__ csr_src,
                          const float* __restrict__ x,
                          const double* __restrict__ mean,
                          const uint32_t* __restrict__ frag,
                          int8_t* __restrict__ H) {
  extern __shared__ uint4 lb[];
  if (blockIdx.x < DEGB) {
    int e = blockIdx.x * 256 + threadIdx.x;
    if (e >= NE) return;
    int dst = ei[e], src = ei[NE + e];
    uint32_t pos = rowptr[dst] + base[dst >> 8] + atomicAdd(&cursor[dst], 1u);
    csr_src[pos] = src;
    return;
  }
  const int blk = blockIdx.x - DEGB;
  const int tot = 8 * 8 * 64;                       // 4096 uint4 = 64 KB
  const uint4* fg = (const uint4*)frag;
  for (int i = threadIdx.x; i < tot; i += 256) lb[i] = fg[i];
  __syncthreads();
  const int lane = threadIdx.x & 63;
  const int wv = threadIdx.x >> 6;
  const int r0 = (blk * 4 + wv) * 16;
  if (r0 >= NN) return;
  const int m = lane & 15, q = lane >> 4;
  const float* xp = x + (size_t)(r0 + m) * DI + q * 16;
  const double* mp0 = mean + q * 16;
  int4v acc[8];
#pragma unroll
  for (int t = 0; t < 8; ++t) acc[t] = (int4v){0, 0, 0, 0};
#pragma unroll
  for (int s = 0; s < 8; ++s) {
    const float* xs = xp + s * 64;
    const double* mp = mp0 + s * 64;
    int4v a;
#pragma unroll
    for (int w4 = 0; w4 < 4; ++w4) {
      float4 f = *(const float4*)(xs + 4 * w4);
      double v0 = (double)f.x - mp[4 * w4 + 0];
      double v1 = (double)f.y - mp[4 * w4 + 1];
      double v2 = (double)f.z - mp[4 * w4 + 2];
      double v3 = (double)f.w - mp[4 * w4 + 3];
      uint32_t o = 0;
      o |= (uint8_t)(int8_t)((v0 > 0.0) ? 1 : ((v0 < 0.0) ? -1 : 0));
      o |= ((uint32_t)(uint8_t)(int8_t)((v1 > 0.0) ? 1 : ((v1 < 0.0) ? -1 : 0))) << 8;
      o |= ((uint32_t)(uint8_t)(int8_t)((v2 > 0.0) ? 1 : ((v2 < 0.0) ? -1 : 0))) << 16;
      o |= ((uint32_t)(uint8_t)(int8_t)((v3 > 0.0) ? 1 : ((v3 < 0.0) ? -1 : 0))) << 24;
      a[w4] = (int)o;
    }
#pragma unroll
    for (int t = 0; t < 8; ++t) {
      int4v b = *(const int4v*)&lb[(s * 8 + t) * 64 + lane];
      acc[t] = __builtin_amdgcn_mfma_i32_16x16x64_i8(a, b, acc[t], 0, 0, 0);
    }
  }
  int8_t* hp = H + (size_t)r0 * DH;
#pragma unroll
  for (int t = 0; t < 8; ++t) {
    int n = t * 16 + m;
#pragma unroll
    for (int r = 0; r < 4; ++r)
      hp[(size_t)(q * 4 + r) * DH + n] = (int8_t)(acc[t][r] >> 1);
  }
}

// ---------------- ternary GEMM via MFMA i8 16x16x64 -----------------------
template <int STEPS, int NT, int C, int SHIFT>
__global__ void gemm_mfma(const int8_t* __restrict__ S,
                          const uint32_t* __restrict__ frag,
                          int8_t* __restrict__ H) {
  extern __shared__ uint4 lb[];
  const int tot = STEPS * NT * 64;
  const uint4* fg = (const uint4*)frag;
  for (int i = threadIdx.x; i < tot; i += 256) lb[i] = fg[i];
  __syncthreads();
  const int lane = threadIdx.x & 63;
  const int wv = threadIdx.x >> 6;
  const int r0 = (blockIdx.x * 4 + wv) * 16;
  if (r0 >= NN) return;                 // NN % 16 == 0
  const int m = lane & 15, q = lane >> 4;
  const int K = STEPS * 64;
  const int8_t* sp = S + (size_t)(r0 + m) * K + q * 16;
  int4v acc[NT];
#pragma unroll
  for (int t = 0; t < NT; ++t) acc[t] = (int4v){0, 0, 0, 0};
#pragma unroll
  for (int s = 0; s < STEPS; ++s) {
    int4v a = *(const int4v*)(sp + (size_t)s * 64);
#pragma unroll
    for (int t = 0; t < NT; ++t) {
      int4v b = *(const int4v*)&lb[(s * NT + t) * 64 + lane];
      acc[t] = __builtin_amdgcn_mfma_i32_16x16x64_i8(a, b, acc[t], 0, 0, 0);
    }
  }
  int8_t* hp = H + (size_t)r0 * C;
#pragma unroll
  for (int t = 0; t < NT; ++t) {
    int n = t * 16 + m;
    if (n < C) {
#pragma unroll
      for (int r = 0; r < 4; ++r)
        hp[(size_t)(q * 4 + r) * C + n] = (int8_t)(acc[t][r] >> SHIFT);
    }
  }
}

// ---- gather (C=128): ORDER-PRESERVING, 1-deep prefetch, base folded in ----
__global__ void gather128(const uint32_t* __restrict__ rowptr,
                          const uint32_t* __restrict__ base,
                          const int* __restrict__ csr_src,
                          const double* __restrict__ dinv,
                          const int8_t* __restrict__ H,
                          const float* __restrict__ b,
                          int8_t* __restrict__ Sout,
                          const double* __restrict__ wsum, double cnt,
                          uint32_t fk0, uint32_t fk1) {
  int d = (int)(((size_t)blockIdx.x * blockDim.x + threadIdx.x) >> 6);
  int lane = threadIdx.x & 63;
  if (d >= NN) return;
  const int g = lane >> 5, p = lane & 31;
  double a0 = 0.0, a1 = 0.0, a2 = 0.0, a3 = 0.0;
  const uint32_t e0 = rowptr[d] + base[d >> 8];
  const uint32_t e1 = (d + 1 < NN) ? (rowptr[d + 1] + base[(d + 1) >> 8]) : NE;
  const int L = (int)(e1 - e0) + 1;               // + self-loop (edge 0)
  for (int c0 = 0; c0 < L; c0 += 64) {
    const int n = min(64, L - c0);
    const int my = c0 + lane;
    int sidx = d;
    if (my > 0 && my < L) sidx = csr_src[e0 + my - 1];
    double wv = dinv[sidx];                       // sidx=d is valid fallback
    int t = 0;
    {
      int sA = 0, sB = 0; double wA = 0.0, wB = 0.0;
      uint32_t hA = 0, hB = 0;
      if (4 <= n) {                               // wave-uniform
        sA = __shfl(sidx, g);      wA = __shfl(wv, g);
        sB = __shfl(sidx, 2 + g);  wB = __shfl(wv, 2 + g);
        hA = *(const uint32_t*)(H + (size_t)sA * DH + 4 * p);
        hB = *(const uint32_t*)(H + (size_t)sB * DH + 4 * p);
      }
      for (; t + 4 <= n; t += 4) {
        const uint32_t cA = hA, cB = hB;
        const double vA = wA, vB = wB;
        if (t + 8 <= n) {                         // prefetch next pair
          sA = __shfl(sidx, t + 4 + g);  wA = __shfl(wv, t + 4 + g);
          sB = __shfl(sidx, t + 6 + g);  wB = __shfl(wv, t + 6 + g);
          hA = *(const uint32_t*)(H + (size_t)sA * DH + 4 * p);
          hB = *(const uint32_t*)(H + (size_t)sB * DH + 4 * p);
        }
        a0 += vA * (double)(int8_t)(cA);
        a1 += vA * (double)(int8_t)(cA >> 8);
        a2 += vA * (double)(int8_t)(cA >> 16);
        a3 += vA * (double)(int8_t)(cA >> 24);
        a0 += vB * (double)(int8_t)(cB);
        a1 += vB * (double)(int8_t)(cB >> 8);
        a2 += vB * (double)(int8_t)(cB >> 16);
        a3 += vB * (double)(int8_t)(cB >> 24);
      }
    }
    for (; t < n; t += 2) {                       // non-divergent tail
      const int j = t + g;
      const bool on = (j < n);
      const int jc = on ? j : 0;
      int s = __shfl(sidx, jc);
      double w = __shfl(wv, jc);
      w = on ? w : 0.0;
      uint32_t hv = *(const uint32_t*)(H + (size_t)s * DH + 4 * p);
      a0 += w * (double)(int8_t)(hv);
      a1 += w * (double)(int8_t)(hv >> 8);
      a2 += w * (double)(int8_t)(hv >> 16);
      a3 += w * (double)(int8_t)(hv >> 24);
    }
  }
  a0 += __shfl_xor(a0, 32);
  a1 += __shfl_xor(a1, 32);
  a2 += __shfl_xor(a2, 32);
  a3 += __shfl_xor(a3, 32);
  double sc = (wsum[0] / cnt) * dinv[d];
  int ch = 4 * p + 2 * g;
  int j0 = d * DH + ch;
  double va = sc * ((g == 0) ? a0 : a2) + (double)b[ch];
  double vb = sc * ((g == 0) ? a1 : a3) + (double)b[ch + 1];
  int s0 = (va > 0.0) ? 1 : ((va < 0.0) ? -1 : 0);
  int s1 = (vb > 0.0) ? 1 : ((vb < 0.0) ? -1 : 0);
  uint32_t r0, r1, bits0, bits1;
  threefry2x32(fk0, fk1, 0u, (uint32_t)j0, &r0, &r1);
  bits0 = r0 ^ r1;
  threefry2x32(fk0, fk1, 0u, (uint32_t)(j0 + 1), &r0, &r1);
  bits1 = r0 ^ r1;
  float u0 = __uint_as_float((bits0 >> 9) | 0x3f800000u) - 1.0f;
  float u1 = __uint_as_float((bits1 >> 9) | 0x3f800000u) - 1.0f;
  uint8_t o0 = (u0 < 0.5f) ? (uint8_t)(int8_t)s0 : (uint8_t)0;
  uint8_t o1 = (u1 < 0.5f) ? (uint8_t)(int8_t)s1 : (uint8_t)0;
  *(uint16_t*)(Sout + j0) = (uint16_t)(o0 | ((uint16_t)o1 << 8));
}

// ---- gather (C=40): ORDER-PRESERVING, base folded in, fused log_softmax ---
__global__ void gather40_lsm(const uint32_t* __restrict__ rowptr,
                             const uint32_t* __restrict__ base,
                             const int* __restrict__ csr_src,
                             const double* __restrict__ dinv,
                             const int8_t* __restrict__ H,
                             const float* __restrict__ b2,
                             const double* __restrict__ wsum,
                             float* __restrict__ out) {
  int d = (int)(((size_t)blockIdx.x * blockDim.x + threadIdx.x) >> 6);
  int lane = threadIdx.x & 63;
  if (d >= NN) return;
  const int g = lane >> 5, p = lane & 31;
  const bool act = (p < 20);
  double a0 = 0.0, a1 = 0.0;
  const uint32_t e0 = rowptr[d] + base[d >> 8];
  const uint32_t e1 = (d + 1 < NN) ? (rowptr[d + 1] + base[(d + 1) >> 8]) : NE;
  const int L = (int)(e1 - e0) + 1;
  for (int c0 = 0; c0 < L; c0 += 64) {
    const int n = min(64, L - c0);
    const int my = c0 + lane;
    int sidx = d;
    if (my > 0 && my < L) sidx = csr_src[e0 + my - 1];
    double wv = dinv[sidx];
    int t = 0;
    {
      int sA = 0, sB = 0; double wA = 0.0, wB = 0.0;
      uint16_t hA = 0, hB = 0;
      if (4 <= n) {
        sA = __shfl(sidx, g);      wA = __shfl(wv, g);
        sB = __shfl(sidx, 2 + g);  wB = __shfl(wv, 2 + g);
        if (act) {
          hA = *(const uint16_t*)(H + (size_t)sA * DO + 2 * p);
          hB = *(const uint16_t*)(H + (size_t)sB * DO + 2 * p);
        }
      }
      for (; t + 4 <= n; t += 4) {
        const uint16_t cA = hA, cB = hB;
        const double vA = wA, vB = wB;
        if (t + 8 <= n) {
          sA = __shfl(sidx, t + 4 + g);  wA = __shfl(wv, t + 4 + g);
          sB = __shfl(sidx, t + 6 + g);  wB = __shfl(wv, t + 6 + g);
          if (act) {
            hA = *(const uint16_t*)(H + (size_t)sA * DO + 2 * p);
            hB = *(const uint16_t*)(H + (size_t)sB * DO + 2 * p);
          }
        }
        if (act) {
          a0 += vA * (double)(int8_t)(cA);
          a1 += vA * (double)(int8_t)(cA >> 8);
          a0 += vB * (double)(int8_t)(cB);
          a1 += vB * (double)(int8_t)(cB >> 8);
        }
      }
    }
    for (; t < n; t += 2) {
      const int j = t + g;
      const bool on = (j < n);
      const int jc = on ? j : 0;
      int s = __shfl(sidx, jc);
      double w = __shfl(wv, jc);
      w = on ? w : 0.0;
      if (act) {
        uint16_t hv = *(const uint16_t*)(H + (size_t)s * DO + 2 * p);
        a0 += w * (double)(int8_t)(hv);
        a1 += w * (double)(int8_t)(hv >> 8);
      }
    }
  }
  a0 += __shfl_xor(a0, 32);
  a1 += __shfl_xor(a1, 32);
  double sc = (wsum[0] / (double)(DH * DO)) * dinv[d];
  const bool lead = (g == 0) && act;
  double v0 = 0.0, v1 = 0.0;
  if (act) {
    v0 = sc * a0 + (double)b2[2 * p];
    v1 = sc * a1 + (double)b2[2 * p + 1];
  }
  double mx = lead ? fmax(v0, v1) : -1.0e300;
  for (int ofs = 32; ofs > 0; ofs >>= 1) mx = fmax(mx, __shfl_xor(mx, ofs));
  float ex = lead ? (expf((float)(v0 - mx)) + expf((float)(v1 - mx))) : 0.f;
  for (int ofs = 32; ofs > 0; ofs >>= 1) ex += __shfl_xor(ex, ofs);
  float l = logf(ex);
  if (lead) {
    float2 o = make_float2((float)(v0 - mx) - l, (float)(v1 - mx) - l);
    *(float2*)(out + (size_t)d * DO + 2 * p) = o;
  }
}

// ---------------- launch ----------------
extern "C" void kernel_launch(void* const* d_in, const int* in_sizes, int n_in,
                              void* d_out, int out_size, void* d_ws, size_t ws_size,
                              hipStream_t stream) {
  (void)in_sizes; (void)n_in; (void)out_size; (void)ws_size;
  const float* x  = (const float*)d_in[0];
  const int*   ei = (const int*)d_in[1];
  const float* w0 = (const float*)d_in[2];
  const float* b0 = (const float*)d_in[3];
  const float* w1 = (const float*)d_in[4];
  const float* b1 = (const float*)d_in[5];
  const float* w2 = (const float*)d_in[6];
  const float* b2 = (const float*)d_in[7];
  float* out = (float*)d_out;

  // ---- workspace carve-up (~17 MB)
  char* wsb = (char*)d_ws;
  double*   mean_d = (double*)wsb;                    // [512] col sums->means
  double*   wsum_d = (double*)(wsb + 4096);           // [3]            pad->4224
  uint32_t* deg_e  = (uint32_t*)(wsb + 4224);         // [NN] edge-only degree
  uint32_t* cursor = (uint32_t*)(wsb + 204224);       // [NN] fill cursors
  // bytes [0, 404224) are zeroed each call
  size_t cur = 404480;
  uint32_t* rowptr = (uint32_t*)(wsb + cur); cur += 200064;   // [NN+1] (pre-base)
  double*   dinv_d = (double*)(wsb + cur);  cur += 400000;
  cur = (cur + 255) & ~255ull;
  uint32_t* bsum = (uint32_t*)(wsb + cur); cur += 1024;       // [NBLK]
  uint32_t* base = (uint32_t*)(wsb + cur); cur += 1024;       // [NBLK]
  int*    csr_src = (int*)(wsb + cur);    cur += (size_t)NE * 4;   // 2.4 MB
  cur = (cur + 255) & ~255ull;
  uint32_t* FR0 = (uint32_t*)(wsb + cur); cur += 8 * 8 * 64 * 16;  // 64 KB
  uint32_t* FR1 = (uint32_t*)(wsb + cur); cur += 2 * 8 * 64 * 16;  // 16 KB
  uint32_t* FR2 = (uint32_t*)(wsb + cur); cur += 2 * 3 * 64 * 16;  // 6 KB
  int8_t* S1  = (int8_t*)(wsb + cur); cur += (size_t)MTOT;         // 6.4 MB
  cur = (cur + 255) & ~255ull;
  int8_t* H8 = (int8_t*)(wsb + cur); cur += (size_t)MTOT;          // 6.4 MB

  // fold_in(key(42), i): key=(0,42); folded = threefry(key, (0,i)) full output
  uint32_t fkA0, fkA1, fkB0, fkB1;
  threefry2x32(0u, 42u, 0u, 0u, &fkA0, &fkA1);
  threefry2x32(0u, 42u, 0u, 1u, &fkB0, &fkB1);

  // zero mean/wsum/deg/cursor (ws is poisoned 0xAA before every call)
  hipMemsetAsync(wsb, 0, 404224, stream);

  // MEGA-1: colsum || deg_edges || wfuse  (2830 blocks)
  prologue_fused<<<CSB + DEGB + 86, 256, 0, stream>>>(
      x, mean_d, ei, deg_e, w0, w1, w2, FR0, FR1, FR2, wsum_d);
  // MEGA-2: scan_blocks || mean_finalize  (198 blocks)
  scan_mean<<<NBLK + 2, 256, 0, stream>>>(deg_e, rowptr, bsum, dinv_d, mean_d);
  scan_bsum<<<1, 256, 0, stream>>>(bsum, base);

  const int node_blocks = (NN * 64) / 256 + 1;          // 12501 waves >= NN
  const size_t sh0 = 8 * 8 * 64 * 16;                   // 64 KB
  const size_t sh1 = 2 * 8 * 64 * 16;                   // 16 KB
  const size_t sh2 = 2 * 3 * 64 * 16;                   // 6 KB

  // MEGA-3: csr_fill || gemm0(bn_sign fused)   (2344 + 782 blocks)
  csr_gemm0<<<DEGB + GEMMB, 256, sh0, stream>>>(ei, rowptr, base, cursor,
                                                csr_src, x, mean_d, FR0, H8);
  gather128<<<node_blocks, 256, 0, stream>>>(rowptr, base, csr_src, dinv_d, H8,
                                             b0, S1, wsum_d + 0,
                                             (double)(DI * DH / 2), fkA0, fkA1);

  // layer 1: K=128 -> DH
  gemm_mfma<2, 8, DH, 0><<<GEMMB, 256, sh1, stream>>>(S1, FR1, H8);
  gather128<<<node_blocks, 256, 0, stream>>>(rowptr, base, csr_src, dinv_d, H8,
                                             b1, S1, wsum_d + 1,
                                             (double)(DH * DH), fkB0, fkB1);

  // layer 2: K=128 -> DO, fused log_softmax
  gemm_mfma<2, 3, DO, 0><<<GEMMB, 256, sh2, stream>>>(S1, FR2, H8);
  gather40_lsm<<<node_blocks, 256, 0, stream>>>(rowptr, base, csr_src, dinv_d,
                                                H8, b2, wsum_d + 2, out);
}

// Round 9
// 371.127 us; speedup vs baseline: 1.0817x; 1.0038x over previous
//
#include <hip/hip_runtime.h>
#include <stdint.h>
#include <stddef.h>

#define NN 50000
#define NE 600000
#define DI 512
#define DH 128
#define DO 40
#define MTOT (NN * DH)   // 6,400,000
#define NBLK ((NN + 255) / 256)   // 196 scan blocks
#define DEGB ((NE + 255) / 256)   // 2344 deg blocks
#define CSB 400                   // colsum blocks (1 chain/thread)
#define GEMMB ((NN / 16 + 3) / 4) // 782 gemm blocks

using int4v = __attribute__((ext_vector_type(4))) int;

// ---------------- threefry2x32 (exact JAX semantics) ----------------
__host__ __device__ inline uint32_t rotl32(uint32_t v, int d) {
  return (v << d) | (v >> (32 - d));
}

__host__ __device__ inline void threefry2x32(uint32_t k0, uint32_t k1,
                                             uint32_t c0, uint32_t c1,
                                             uint32_t* o0, uint32_t* o1) {
  uint32_t ks0 = k0, ks1 = k1, ks2 = k0 ^ k1 ^ 0x1BD11BDAu;
  uint32_t x0 = c0 + ks0, x1 = c1 + ks1;
  const int R0[4] = {13, 15, 26, 6};
  const int R1[4] = {17, 29, 16, 24};
#define TF_R4(R) { x0 += x1; x1 = rotl32(x1, R[0]); x1 ^= x0; \
                   x0 += x1; x1 = rotl32(x1, R[1]); x1 ^= x0; \
                   x0 += x1; x1 = rotl32(x1, R[2]); x1 ^= x0; \
                   x0 += x1; x1 = rotl32(x1, R[3]); x1 ^= x0; }
  TF_R4(R0); x0 += ks1; x1 += ks2 + 1u;
  TF_R4(R1); x0 += ks2; x1 += ks0 + 2u;
  TF_R4(R0); x0 += ks0; x1 += ks1 + 3u;
  TF_R4(R1); x0 += ks1; x1 += ks2 + 4u;
  TF_R4(R0); x0 += ks2; x1 += ks0 + 5u;
#undef TF_R4
  *o0 = x0; *o1 = x1;
}

// ---- BN column sums — chains (grp 0..199, col 0..511), 1 chain/thread -----
// NUMERICALLY LIVE: per-chain f64 add ORDER unchanged (rows ascending).
// 25 row values are ASM OPERANDS -> all live in regs -> 25 loads in flight.
__device__ inline void colsum_body(const float* __restrict__ x,
                                   double* __restrict__ colsum, int blk) {
  const int t = threadIdx.x;
  const int grp = blk >> 1;                    // 0..199
  const int col = ((blk & 1) << 8) + t;        // 0..511
  const float* xp = x + (size_t)grp * 250 * DI + col;
  double s = 0.0;
  for (int i = 0; i < 10; ++i) {
    float f0  = xp[0 * DI],  f1  = xp[1 * DI],  f2  = xp[2 * DI];
    float f3  = xp[3 * DI],  f4  = xp[4 * DI],  f5  = xp[5 * DI];
    float f6  = xp[6 * DI],  f7  = xp[7 * DI],  f8  = xp[8 * DI];
    float f9  = xp[9 * DI],  f10 = xp[10 * DI], f11 = xp[11 * DI];
    float f12 = xp[12 * DI], f13 = xp[13 * DI], f14 = xp[14 * DI];
    float f15 = xp[15 * DI], f16 = xp[16 * DI], f17 = xp[17 * DI];
    float f18 = xp[18 * DI], f19 = xp[19 * DI], f20 = xp[20 * DI];
    float f21 = xp[21 * DI], f22 = xp[22 * DI], f23 = xp[23 * DI];
    float f24 = xp[24 * DI];
    asm volatile("" :: "v"(f0), "v"(f1), "v"(f2), "v"(f3), "v"(f4),
                       "v"(f5), "v"(f6), "v"(f7), "v"(f8), "v"(f9),
                       "v"(f10), "v"(f11), "v"(f12), "v"(f13), "v"(f14),
                       "v"(f15), "v"(f16), "v"(f17), "v"(f18), "v"(f19),
                       "v"(f20), "v"(f21), "v"(f22), "v"(f23), "v"(f24));
    s += (double)f0;  s += (double)f1;  s += (double)f2;  s += (double)f3;
    s += (double)f4;  s += (double)f5;  s += (double)f6;  s += (double)f7;
    s += (double)f8;  s += (double)f9;  s += (double)f10; s += (double)f11;
    s += (double)f12; s += (double)f13; s += (double)f14; s += (double)f15;
    s += (double)f16; s += (double)f17; s += (double)f18; s += (double)f19;
    s += (double)f20; s += (double)f21; s += (double)f22; s += (double)f23;
    s += (double)f24;                       // ascending row order, unchanged
    xp += 25 * DI;
  }
  unsafeAtomicAdd(&colsum[col], s);
}

// ---- fused weight prep body: MFMA B-fragments from float w + sum|w| -------
__device__ inline void wfuse_body(const float* __restrict__ w,
                                  uint32_t* __restrict__ frag,
                                  double* __restrict__ slot,
                                  int K, int C, int NT, int blk,
                                  double* red) {
  int steps = K >> 6;
  int total = steps * NT * 64 * 4;
  int idx = blk * 256 + threadIdx.x;
  double a = 0.0;
  if (idx < total) {
    int dw = idx & 3;
    int lane = (idx >> 2) & 63;
    int rest = idx >> 8;
    int t = rest % NT;
    int s = rest / NT;
    int n = t * 16 + (lane & 15);
    int kbase = s * 64 + (lane >> 4) * 16 + dw * 4;
    uint32_t v = 0;
    if (n < C) {
#pragma unroll
      for (int j = 0; j < 4; ++j) {
        float wv = w[(size_t)(kbase + j) * C + n];
        uint32_t sg = (uint8_t)(int8_t)((wv > 0.f) ? 1 : ((wv < 0.f) ? -1 : 0));
        v |= sg << (8 * j);
        a += (double)fabsf(wv);
      }
    }
    frag[idx] = v;
  }
  red[threadIdx.x] = a;
  __syncthreads();
  for (int ofs = 128; ofs > 0; ofs >>= 1) {
    if (threadIdx.x < ofs) red[threadIdx.x] += red[threadIdx.x + ofs];
    __syncthreads();
  }
  if (threadIdx.x == 0) unsafeAtomicAdd(slot, red[0]);
}

// ---- MEGA-1: colsum [0,400) || deg_edges [400,2744) || wfuse [2744,2830) ---
__global__ void prologue_fused(const float* __restrict__ x,
                               double* __restrict__ colsum,
                               const int* __restrict__ ei,
                               uint32_t* __restrict__ deg,
                               const float* __restrict__ w0,
                               const float* __restrict__ w1,
                               const float* __restrict__ w2,
                               uint32_t* __restrict__ f0,
                               uint32_t* __restrict__ f1,
                               uint32_t* __restrict__ f2,
                               double* __restrict__ slots) {
  __shared__ double red[256];
  int b = blockIdx.x;
  if (b < CSB) {
    colsum_body(x, colsum, b);
  } else if (b < CSB + DEGB) {
    int e = (b - CSB) * 256 + threadIdx.x;
    if (e < NE) atomicAdd(&deg[ei[e]], 1u);   // ei[0:E] = destinations
  } else {
    int wb = b - (CSB + DEGB);
    if (wb < 64)       wfuse_body(w0, f0, slots + 0, DI, DH, 8, wb,      red);
    else if (wb < 80)  wfuse_body(w1, f1, slots + 1, DH, DH, 8, wb - 64, red);
    else               wfuse_body(w2, f2, slots + 2, DH, DO, 3, wb - 80, red);
  }
}

// ---- MEGA-2: scan_blocks [0,196) || mean_finalize [196,198) ----------------
__global__ void scan_mean(const uint32_t* __restrict__ deg,
                          uint32_t* __restrict__ rowptr,
                          uint32_t* __restrict__ bsum,
                          double* __restrict__ dinv,
                          double* __restrict__ colsum) {
  __shared__ uint32_t bs[256];
  int b = blockIdx.x;
  int t = threadIdx.x;
  if (b < NBLK) {
    int i = b * 256 + t;
    uint32_t v = (i < NN) ? deg[i] : 0u;
    if (i < NN) dinv[i] = 1.0 / sqrt((double)(v + 1u));   // +1 self-loop
    bs[t] = v;
    __syncthreads();
    for (int ofs = 1; ofs < 256; ofs <<= 1) {
      uint32_t add = (t >= ofs) ? bs[t - ofs] : 0u;
      __syncthreads();
      bs[t] += add;
      __syncthreads();
    }
    if (i < NN) rowptr[i] = bs[t] - v;     // exclusive within block (pre-base)
    if (t == 255) bsum[b] = bs[255];
  } else {
    int c = (b - NBLK) * 256 + t;
    if (c < DI) colsum[c] = colsum[c] / (double)NN;
  }
}

__global__ void scan_bsum(const uint32_t* __restrict__ bsum,
                          uint32_t* __restrict__ base) {
  __shared__ uint32_t bs[256];
  int t = threadIdx.x;
  uint32_t v = (t < NBLK) ? bsum[t] : 0u;
  bs[t] = v;
  __syncthreads();
  for (int ofs = 1; ofs < 256; ofs <<= 1) {
    uint32_t add = (t >= ofs) ? bs[t - ofs] : 0u;
    __syncthreads();
    bs[t] += add;
    __syncthreads();
  }
  if (t < NBLK) base[t] = bs[t] - v;
}

// ---- MEGA-3: csr_fill [0,2344) || gemm0 [2344,3126) ------------------------
// r8 lesson: 64KB dynamic LDS for ALL blocks capped occupancy at 2 blocks/CU
// (15.4%) — the csr blocks need none. Fix: NO LDS; gemm0 reads B-fragments
// straight from global (frag = 64KB, same addresses every block -> L2-hit).
// Occupancy now VGPR-bound (~8 blocks/CU).
__global__ void csr_gemm0(const int* __restrict__ ei,
                          const uint32_t* __restrict__ rowptr,
                          const uint32_t* __restrict__ base,
                          uint32_t* __restrict__ cursor,
                          int* __restrict__ csr_src,
                          const float* __restrict__ x,
                          const double* __restrict__ mean,
                          const uint32_t* __restrict__ frag,
                          int8_t* __restrict__ H) {
  if (blockIdx.x < DEGB) {
    int e = blockIdx.x * 256 + threadIdx.x;
    if (e >= NE) return;
    int dst = ei[e], src = ei[NE + e];
    uint32_t pos = rowptr[dst] + base[dst >> 8] + atomicAdd(&cursor[dst], 1u);
    csr_src[pos] = src;
    return;
  }
  const int blk = blockIdx.x - DEGB;
  const uint4* fg = (const uint4*)frag;
  const int lane = threadIdx.x & 63;
  const int wv = threadIdx.x >> 6;
  const int r0 = (blk * 4 + wv) * 16;
  if (r0 >= NN) return;
  const int m = lane & 15, q = lane >> 4;
  const float* xp = x + (size_t)(r0 + m) * DI + q * 16;
  const double* mp0 = mean + q * 16;
  int4v acc[8];
#pragma unroll
  for (int t = 0; t < 8; ++t) acc[t] = (int4v){0, 0, 0, 0};
#pragma unroll
  for (int s = 0; s < 8; ++s) {
    const float* xs = xp + s * 64;
    const double* mp = mp0 + s * 64;
    int4v a;
#pragma unroll
    for (int w4 = 0; w4 < 4; ++w4) {
      float4 f = *(const float4*)(xs + 4 * w4);
      double v0 = (double)f.x - mp[4 * w4 + 0];
      double v1 = (double)f.y - mp[4 * w4 + 1];
      double v2 = (double)f.z - mp[4 * w4 + 2];
      double v3 = (double)f.w - mp[4 * w4 + 3];
      uint32_t o = 0;
      o |= (uint8_t)(int8_t)((v0 > 0.0) ? 1 : ((v0 < 0.0) ? -1 : 0));
      o |= ((uint32_t)(uint8_t)(int8_t)((v1 > 0.0) ? 1 : ((v1 < 0.0) ? -1 : 0))) << 8;
      o |= ((uint32_t)(uint8_t)(int8_t)((v2 > 0.0) ? 1 : ((v2 < 0.0) ? -1 : 0))) << 16;
      o |= ((uint32_t)(uint8_t)(int8_t)((v3 > 0.0) ? 1 : ((v3 < 0.0) ? -1 : 0))) << 24;
      a[w4] = (int)o;
    }
#pragma unroll
    for (int t = 0; t < 8; ++t) {
      int4v b = *(const int4v*)&fg[(s * 8 + t) * 64 + lane];   // L2-resident
      acc[t] = __builtin_amdgcn_mfma_i32_16x16x64_i8(a, b, acc[t], 0, 0, 0);
    }
  }
  int8_t* hp = H + (size_t)r0 * DH;
#pragma unroll
  for (int t = 0; t < 8; ++t) {
    int n = t * 16 + m;
#pragma unroll
    for (int r = 0; r < 4; ++r)
      hp[(size_t)(q * 4 + r) * DH + n] = (int8_t)(acc[t][r] >> 1);
  }
}

// ---------------- ternary GEMM via MFMA i8 16x16x64 -----------------------
template <int STEPS, int NT, int C, int SHIFT>
__global__ void gemm_mfma(const int8_t* __restrict__ S,
                          const uint32_t* __restrict__ frag,
                          int8_t* __restrict__ H) {
  extern __shared__ uint4 lb[];
  const int tot = STEPS * NT * 64;
  const uint4* fg = (const uint4*)frag;
  for (int i = threadIdx.x; i < tot; i += 256) lb[i] = fg[i];
  __syncthreads();
  const int lane = threadIdx.x & 63;
  const int wv = threadIdx.x >> 6;
  const int r0 = (blockIdx.x * 4 + wv) * 16;
  if (r0 >= NN) return;                 // NN % 16 == 0
  const int m = lane & 15, q = lane >> 4;
  const int K = STEPS * 64;
  const int8_t* sp = S + (size_t)(r0 + m) * K + q * 16;
  int4v acc[NT];
#pragma unroll
  for (int t = 0; t < NT; ++t) acc[t] = (int4v){0, 0, 0, 0};
#pragma unroll
  for (int s = 0; s < STEPS; ++s) {
    int4v a = *(const int4v*)(sp + (size_t)s * 64);
#pragma unroll
    for (int t = 0; t < NT; ++t) {
      int4v b = *(const int4v*)&lb[(s * NT + t) * 64 + lane];
      acc[t] = __builtin_amdgcn_mfma_i32_16x16x64_i8(a, b, acc[t], 0, 0, 0);
    }
  }
  int8_t* hp = H + (size_t)r0 * C;
#pragma unroll
  for (int t = 0; t < NT; ++t) {
    int n = t * 16 + m;
    if (n < C) {
#pragma unroll
      for (int r = 0; r < 4; ++r)
        hp[(size_t)(q * 4 + r) * C + n] = (int8_t)(acc[t][r] >> SHIFT);
    }
  }
}

// ---- gather (C=128): ORDER-PRESERVING, 1-deep prefetch, base folded in ----
__global__ void gather128(const uint32_t* __restrict__ rowptr,
                          const uint32_t* __restrict__ base,
                          const int* __restrict__ csr_src,
                          const double* __restrict__ dinv,
                          const int8_t* __restrict__ H,
                          const float* __restrict__ b,
                          int8_t* __restrict__ Sout,
                          const double* __restrict__ wsum, double cnt,
                          uint32_t fk0, uint32_t fk1) {
  int d = (int)(((size_t)blockIdx.x * blockDim.x + threadIdx.x) >> 6);
  int lane = threadIdx.x & 63;
  if (d >= NN) return;
  const int g = lane >> 5, p = lane & 31;
  double a0 = 0.0, a1 = 0.0, a2 = 0.0, a3 = 0.0;
  const uint32_t e0 = rowptr[d] + base[d >> 8];
  const uint32_t e1 = (d + 1 < NN) ? (rowptr[d + 1] + base[(d + 1) >> 8]) : NE;
  const int L = (int)(e1 - e0) + 1;               // + self-loop (edge 0)
  for (int c0 = 0; c0 < L; c0 += 64) {
    const int n = min(64, L - c0);
    const int my = c0 + lane;
    int sidx = d;
    if (my > 0 && my < L) sidx = csr_src[e0 + my - 1];
    double wv = dinv[sidx];                       // sidx=d is valid fallback
    int t = 0;
    {
      int sA = 0, sB = 0; double wA = 0.0, wB = 0.0;
      uint32_t hA = 0, hB = 0;
      if (4 <= n) {                               // wave-uniform
        sA = __shfl(sidx, g);      wA = __shfl(wv, g);
        sB = __shfl(sidx, 2 + g);  wB = __shfl(wv, 2 + g);
        hA = *(const uint32_t*)(H + (size_t)sA * DH + 4 * p);
        hB = *(const uint32_t*)(H + (size_t)sB * DH + 4 * p);
      }
      for (; t + 4 <= n; t += 4) {
        const uint32_t cA = hA, cB = hB;
        const double vA = wA, vB = wB;
        if (t + 8 <= n) {                         // prefetch next pair
          sA = __shfl(sidx, t + 4 + g);  wA = __shfl(wv, t + 4 + g);
          sB = __shfl(sidx, t + 6 + g);  wB = __shfl(wv, t + 6 + g);
          hA = *(const uint32_t*)(H + (size_t)sA * DH + 4 * p);
          hB = *(const uint32_t*)(H + (size_t)sB * DH + 4 * p);
        }
        a0 += vA * (double)(int8_t)(cA);
        a1 += vA * (double)(int8_t)(cA >> 8);
        a2 += vA * (double)(int8_t)(cA >> 16);
        a3 += vA * (double)(int8_t)(cA >> 24);
        a0 += vB * (double)(int8_t)(cB);
        a1 += vB * (double)(int8_t)(cB >> 8);
        a2 += vB * (double)(int8_t)(cB >> 16);
        a3 += vB * (double)(int8_t)(cB >> 24);
      }
    }
    for (; t < n; t += 2) {                       // non-divergent tail
      const int j = t + g;
      const bool on = (j < n);
      const int jc = on ? j : 0;
      int s = __shfl(sidx, jc);
      double w = __shfl(wv, jc);
      w = on ? w : 0.0;
      uint32_t hv = *(const uint32_t*)(H + (size_t)s * DH + 4 * p);
      a0 += w * (double)(int8_t)(hv);
      a1 += w * (double)(int8_t)(hv >> 8);
      a2 += w * (double)(int8_t)(hv >> 16);
      a3 += w * (double)(int8_t)(hv >> 24);
    }
  }
  a0 += __shfl_xor(a0, 32);
  a1 += __shfl_xor(a1, 32);
  a2 += __shfl_xor(a2, 32);
  a3 += __shfl_xor(a3, 32);
  double sc = (wsum[0] / cnt) * dinv[d];
  int ch = 4 * p + 2 * g;
  int j0 = d * DH + ch;
  double va = sc * ((g == 0) ? a0 : a2) + (double)b[ch];
  double vb = sc * ((g == 0) ? a1 : a3) + (double)b[ch + 1];
  int s0 = (va > 0.0) ? 1 : ((va < 0.0) ? -1 : 0);
  int s1 = (vb > 0.0) ? 1 : ((vb < 0.0) ? -1 : 0);
  uint32_t r0, r1, bits0, bits1;
  threefry2x32(fk0, fk1, 0u, (uint32_t)j0, &r0, &r1);
  bits0 = r0 ^ r1;
  threefry2x32(fk0, fk1, 0u, (uint32_t)(j0 + 1), &r0, &r1);
  bits1 = r0 ^ r1;
  float u0 = __uint_as_float((bits0 >> 9) | 0x3f800000u) - 1.0f;
  float u1 = __uint_as_float((bits1 >> 9) | 0x3f800000u) - 1.0f;
  uint8_t o0 = (u0 < 0.5f) ? (uint8_t)(int8_t)s0 : (uint8_t)0;
  uint8_t o1 = (u1 < 0.5f) ? (uint8_t)(int8_t)s1 : (uint8_t)0;
  *(uint16_t*)(Sout + j0) = (uint16_t)(o0 | ((uint16_t)o1 << 8));
}

// ---- gather (C=40): ORDER-PRESERVING, base folded in, fused log_softmax ---
__global__ void gather40_lsm(const uint32_t* __restrict__ rowptr,
                             const uint32_t* __restrict__ base,
                             const int* __restrict__ csr_src,
                             const double* __restrict__ dinv,
                             const int8_t* __restrict__ H,
                             const float* __restrict__ b2,
                             const double* __restrict__ wsum,
                             float* __restrict__ out) {
  int d = (int)(((size_t)blockIdx.x * blockDim.x + threadIdx.x) >> 6);
  int lane = threadIdx.x & 63;
  if (d >= NN) return;
  const int g = lane >> 5, p = lane & 31;
  const bool act = (p < 20);
  double a0 = 0.0, a1 = 0.0;
  const uint32_t e0 = rowptr[d] + base[d >> 8];
  const uint32_t e1 = (d + 1 < NN) ? (rowptr[d + 1] + base[(d + 1) >> 8]) : NE;
  const int L = (int)(e1 - e0) + 1;
  for (int c0 = 0; c0 < L; c0 += 64) {
    const int n = min(64, L - c0);
    const int my = c0 + lane;
    int sidx = d;
    if (my > 0 && my < L) sidx = csr_src[e0 + my - 1];
    double wv = dinv[sidx];
    int t = 0;
    {
      int sA = 0, sB = 0; double wA = 0.0, wB = 0.0;
      uint16_t hA = 0, hB = 0;
      if (4 <= n) {
        sA = __shfl(sidx, g);      wA = __shfl(wv, g);
        sB = __shfl(sidx, 2 + g);  wB = __shfl(wv, 2 + g);
        if (act) {
          hA = *(const uint16_t*)(H + (size_t)sA * DO + 2 * p);
          hB = *(const uint16_t*)(H + (size_t)sB * DO + 2 * p);
        }
      }
      for (; t + 4 <= n; t += 4) {
        const uint16_t cA = hA, cB = hB;
        const double vA = wA, vB = wB;
        if (t + 8 <= n) {
          sA = __shfl(sidx, t + 4 + g);  wA = __shfl(wv, t + 4 + g);
          sB = __shfl(sidx, t + 6 + g);  wB = __shfl(wv, t + 6 + g);
          if (act) {
            hA = *(const uint16_t*)(H + (size_t)sA * DO + 2 * p);
            hB = *(const uint16_t*)(H + (size_t)sB * DO + 2 * p);
          }
        }
        if (act) {
          a0 += vA * (double)(int8_t)(cA);
          a1 += vA * (double)(int8_t)(cA >> 8);
          a0 += vB * (double)(int8_t)(cB);
          a1 += vB * (double)(int8_t)(cB >> 8);
        }
      }
    }
    for (; t < n; t += 2) {
      const int j = t + g;
      const bool on = (j < n);
      const int jc = on ? j : 0;
      int s = __shfl(sidx, jc);
      double w = __shfl(wv, jc);
      w = on ? w : 0.0;
      if (act) {
        uint16_t hv = *(const uint16_t*)(H + (size_t)s * DO + 2 * p);
        a0 += w * (double)(int8_t)(hv);
        a1 += w * (double)(int8_t)(hv >> 8);
      }
    }
  }
  a0 += __shfl_xor(a0, 32);
  a1 += __shfl_xor(a1, 32);
  double sc = (wsum[0] / (double)(DH * DO)) * dinv[d];
  const bool lead = (g == 0) && act;
  double v0 = 0.0, v1 = 0.0;
  if (act) {
    v0 = sc * a0 + (double)b2[2 * p];
    v1 = sc * a1 + (double)b2[2 * p + 1];
  }
  double mx = lead ? fmax(v0, v1) : -1.0e300;
  for (int ofs = 32; ofs > 0; ofs >>= 1) mx = fmax(mx, __shfl_xor(mx, ofs));
  float ex = lead ? (expf((float)(v0 - mx)) + expf((float)(v1 - mx))) : 0.f;
  for (int ofs = 32; ofs > 0; ofs >>= 1) ex += __shfl_xor(ex, ofs);
  float l = logf(ex);
  if (lead) {
    float2 o = make_float2((float)(v0 - mx) - l, (float)(v1 - mx) - l);
    *(float2*)(out + (size_t)d * DO + 2 * p) = o;
  }
}

// ---------------- launch ----------------
extern "C" void kernel_launch(void* const* d_in, const int* in_sizes, int n_in,
                              void* d_out, int out_size, void* d_ws, size_t ws_size,
                              hipStream_t stream) {
  (void)in_sizes; (void)n_in; (void)out_size; (void)ws_size;
  const float* x  = (const float*)d_in[0];
  const int*   ei = (const int*)d_in[1];
  const float* w0 = (const float*)d_in[2];
  const float* b0 = (const float*)d_in[3];
  const float* w1 = (const float*)d_in[4];
  const float* b1 = (const float*)d_in[5];
  const float* w2 = (const float*)d_in[6];
  const float* b2 = (const float*)d_in[7];
  float* out = (float*)d_out;

  // ---- workspace carve-up (~17 MB)
  char* wsb = (char*)d_ws;
  double*   mean_d = (double*)wsb;                    // [512] col sums->means
  double*   wsum_d = (double*)(wsb + 4096);           // [3]            pad->4224
  uint32_t* deg_e  = (uint32_t*)(wsb + 4224);         // [NN] edge-only degree
  uint32_t* cursor = (uint32_t*)(wsb + 204224);       // [NN] fill cursors
  // bytes [0, 404224) are zeroed each call
  size_t cur = 404480;
  uint32_t* rowptr = (uint32_t*)(wsb + cur); cur += 200064;   // [NN+1] (pre-base)
  double*   dinv_d = (double*)(wsb + cur);  cur += 400000;
  cur = (cur + 255) & ~255ull;
  uint32_t* bsum = (uint32_t*)(wsb + cur); cur += 1024;       // [NBLK]
  uint32_t* base = (uint32_t*)(wsb + cur); cur += 1024;       // [NBLK]
  int*    csr_src = (int*)(wsb + cur);    cur += (size_t)NE * 4;   // 2.4 MB
  cur = (cur + 255) & ~255ull;
  uint32_t* FR0 = (uint32_t*)(wsb + cur); cur += 8 * 8 * 64 * 16;  // 64 KB
  uint32_t* FR1 = (uint32_t*)(wsb + cur); cur += 2 * 8 * 64 * 16;  // 16 KB
  uint32_t* FR2 = (uint32_t*)(wsb + cur); cur += 2 * 3 * 64 * 16;  // 6 KB
  int8_t* S1  = (int8_t*)(wsb + cur); cur += (size_t)MTOT;         // 6.4 MB
  cur = (cur + 255) & ~255ull;
  int8_t* H8 = (int8_t*)(wsb + cur); cur += (size_t)MTOT;          // 6.4 MB

  // fold_in(key(42), i): key=(0,42); folded = threefry(key, (0,i)) full output
  uint32_t fkA0, fkA1, fkB0, fkB1;
  threefry2x32(0u, 42u, 0u, 0u, &fkA0, &fkA1);
  threefry2x32(0u, 42u, 0u, 1u, &fkB0, &fkB1);

  // zero mean/wsum/deg/cursor (ws is poisoned 0xAA before every call)
  hipMemsetAsync(wsb, 0, 404224, stream);

  // MEGA-1: colsum || deg_edges || wfuse  (2830 blocks)
  prologue_fused<<<CSB + DEGB + 86, 256, 0, stream>>>(
      x, mean_d, ei, deg_e, w0, w1, w2, FR0, FR1, FR2, wsum_d);
  // MEGA-2: scan_blocks || mean_finalize  (198 blocks)
  scan_mean<<<NBLK + 2, 256, 0, stream>>>(deg_e, rowptr, bsum, dinv_d, mean_d);
  scan_bsum<<<1, 256, 0, stream>>>(bsum, base);

  const int node_blocks = (NN * 64) / 256 + 1;          // 12501 waves >= NN
  const size_t sh1 = 2 * 8 * 64 * 16;                   // 16 KB
  const size_t sh2 = 2 * 3 * 64 * 16;                   // 6 KB

  // MEGA-3: csr_fill || gemm0(bn_sign fused), NO LDS (r8 occupancy fix)
  csr_gemm0<<<DEGB + GEMMB, 256, 0, stream>>>(ei, rowptr, base, cursor,
                                              csr_src, x, mean_d, FR0, H8);
  gather128<<<node_blocks, 256, 0, stream>>>(rowptr, base, csr_src, dinv_d, H8,
                                             b0, S1, wsum_d + 0,
                                             (double)(DI * DH / 2), fkA0, fkA1);

  // layer 1: K=128 -> DH
  gemm_mfma<2, 8, DH, 0><<<GEMMB, 256, sh1, stream>>>(S1, FR1, H8);
  gather128<<<node_blocks, 256, 0, stream>>>(rowptr, base, csr_src, dinv_d, H8,
                                             b1, S1, wsum_d + 1,
                                             (double)(DH * DH), fkB0, fkB1);

  // layer 2: K=128 -> DO, fused log_softmax
  gemm_mfma<2, 3, DO, 0><<<GEMMB, 256, sh2, stream>>>(S1, FR2, H8);
  gather40_lsm<<<node_blocks, 256, 0, stream>>>(rowptr, base, csr_src, dinv_d,
                                                H8, b2, wsum_d + 2, out);
}

// Round 10
// 369.354 us; speedup vs baseline: 1.0869x; 1.0048x over previous
//
#include <hip/hip_runtime.h>
#include <stdint.h>
#include <stddef.h>

#define NN 50000
#define NE 600000
#define DI 512
#define DH 128
#define DO 40
#define MTOT (NN * DH)   // 6,400,000
#define NBLK ((NN + 255) / 256)   // 196 scan blocks
#define CSB 400                   // colsum blocks (1 chain/thread)
#define GEMMB ((NN / 16 + 3) / 4) // 782 gemm blocks
#define DEG4B ((NE / 4 + 255) / 256)   // 586 blocks, 4 edges/thread

using int4v = __attribute__((ext_vector_type(4))) int;

// ---------------- threefry2x32 (exact JAX semantics) ----------------
__host__ __device__ inline uint32_t rotl32(uint32_t v, int d) {
  return (v << d) | (v >> (32 - d));
}

__host__ __device__ inline void threefry2x32(uint32_t k0, uint32_t k1,
                                             uint32_t c0, uint32_t c1,
                                             uint32_t* o0, uint32_t* o1) {
  uint32_t ks0 = k0, ks1 = k1, ks2 = k0 ^ k1 ^ 0x1BD11BDAu;
  uint32_t x0 = c0 + ks0, x1 = c1 + ks1;
  const int R0[4] = {13, 15, 26, 6};
  const int R1[4] = {17, 29, 16, 24};
#define TF_R4(R) { x0 += x1; x1 = rotl32(x1, R[0]); x1 ^= x0; \
                   x0 += x1; x1 = rotl32(x1, R[1]); x1 ^= x0; \
                   x0 += x1; x1 = rotl32(x1, R[2]); x1 ^= x0; \
                   x0 += x1; x1 = rotl32(x1, R[3]); x1 ^= x0; }
  TF_R4(R0); x0 += ks1; x1 += ks2 + 1u;
  TF_R4(R1); x0 += ks2; x1 += ks0 + 2u;
  TF_R4(R0); x0 += ks0; x1 += ks1 + 3u;
  TF_R4(R1); x0 += ks1; x1 += ks2 + 4u;
  TF_R4(R0); x0 += ks2; x1 += ks0 + 5u;
#undef TF_R4
  *o0 = x0; *o1 = x1;
}

// ---- BN column sums — chains (grp 0..199, col 0..511), 1 chain/thread -----
// NUMERICALLY LIVE: per-chain f64 add ORDER unchanged (rows ascending).
// 25 row values are ASM OPERANDS -> all live in regs -> 25 loads in flight.
__device__ inline void colsum_body(const float* __restrict__ x,
                                   double* __restrict__ colsum, int blk) {
  const int t = threadIdx.x;
  const int grp = blk >> 1;                    // 0..199
  const int col = ((blk & 1) << 8) + t;        // 0..511
  const float* xp = x + (size_t)grp * 250 * DI + col;
  double s = 0.0;
  for (int i = 0; i < 10; ++i) {
    float f0  = xp[0 * DI],  f1  = xp[1 * DI],  f2  = xp[2 * DI];
    float f3  = xp[3 * DI],  f4  = xp[4 * DI],  f5  = xp[5 * DI];
    float f6  = xp[6 * DI],  f7  = xp[7 * DI],  f8  = xp[8 * DI];
    float f9  = xp[9 * DI],  f10 = xp[10 * DI], f11 = xp[11 * DI];
    float f12 = xp[12 * DI], f13 = xp[13 * DI], f14 = xp[14 * DI];
    float f15 = xp[15 * DI], f16 = xp[16 * DI], f17 = xp[17 * DI];
    float f18 = xp[18 * DI], f19 = xp[19 * DI], f20 = xp[20 * DI];
    float f21 = xp[21 * DI], f22 = xp[22 * DI], f23 = xp[23 * DI];
    float f24 = xp[24 * DI];
    asm volatile("" :: "v"(f0), "v"(f1), "v"(f2), "v"(f3), "v"(f4),
                       "v"(f5), "v"(f6), "v"(f7), "v"(f8), "v"(f9),
                       "v"(f10), "v"(f11), "v"(f12), "v"(f13), "v"(f14),
                       "v"(f15), "v"(f16), "v"(f17), "v"(f18), "v"(f19),
                       "v"(f20), "v"(f21), "v"(f22), "v"(f23), "v"(f24));
    s += (double)f0;  s += (double)f1;  s += (double)f2;  s += (double)f3;
    s += (double)f4;  s += (double)f5;  s += (double)f6;  s += (double)f7;
    s += (double)f8;  s += (double)f9;  s += (double)f10; s += (double)f11;
    s += (double)f12; s += (double)f13; s += (double)f14; s += (double)f15;
    s += (double)f16; s += (double)f17; s += (double)f18; s += (double)f19;
    s += (double)f20; s += (double)f21; s += (double)f22; s += (double)f23;
    s += (double)f24;                       // ascending row order, unchanged
    xp += 25 * DI;
  }
  unsafeAtomicAdd(&colsum[col], s);
}

// ---- fused weight prep body: MFMA B-fragments from float w + sum|w| -------
__device__ inline void wfuse_body(const float* __restrict__ w,
                                  uint32_t* __restrict__ frag,
                                  double* __restrict__ slot,
                                  int K, int C, int NT, int blk,
                                  double* red) {
  int steps = K >> 6;
  int total = steps * NT * 64 * 4;
  int idx = blk * 256 + threadIdx.x;
  double a = 0.0;
  if (idx < total) {
    int dw = idx & 3;
    int lane = (idx >> 2) & 63;
    int rest = idx >> 8;
    int t = rest % NT;
    int s = rest / NT;
    int n = t * 16 + (lane & 15);
    int kbase = s * 64 + (lane >> 4) * 16 + dw * 4;
    uint32_t v = 0;
    if (n < C) {
#pragma unroll
      for (int j = 0; j < 4; ++j) {
        float wv = w[(size_t)(kbase + j) * C + n];
        uint32_t sg = (uint8_t)(int8_t)((wv > 0.f) ? 1 : ((wv < 0.f) ? -1 : 0));
        v |= sg << (8 * j);
        a += (double)fabsf(wv);
      }
    }
    frag[idx] = v;
  }
  red[threadIdx.x] = a;
  __syncthreads();
  for (int ofs = 128; ofs > 0; ofs >>= 1) {
    if (threadIdx.x < ofs) red[threadIdx.x] += red[threadIdx.x + ofs];
    __syncthreads();
  }
  if (threadIdx.x == 0) unsafeAtomicAdd(slot, red[0]);
}

// ---- MEGA-1: colsum [0,400) || deg4 [400,986) || wfuse [986,1072) ----------
// deg: 4 edges/thread — one int4 load + 4 independent atomic chains (MLP x4).
__global__ void prologue_fused(const float* __restrict__ x,
                               double* __restrict__ colsum,
                               const int* __restrict__ ei,
                               uint32_t* __restrict__ deg,
                               const float* __restrict__ w0,
                               const float* __restrict__ w1,
                               const float* __restrict__ w2,
                               uint32_t* __restrict__ f0,
                               uint32_t* __restrict__ f1,
                               uint32_t* __restrict__ f2,
                               double* __restrict__ slots) {
  __shared__ double red[256];
  int b = blockIdx.x;
  if (b < CSB) {
    colsum_body(x, colsum, b);
  } else if (b < CSB + DEG4B) {
    int idx = (b - CSB) * 256 + threadIdx.x;      // edge quad index
    if (idx < NE / 4) {
      int4 d4 = *(const int4*)(ei + 4 * idx);     // 4 dsts, coalesced 16B
      atomicAdd(&deg[d4.x], 1u);
      atomicAdd(&deg[d4.y], 1u);
      atomicAdd(&deg[d4.z], 1u);
      atomicAdd(&deg[d4.w], 1u);
    }
  } else {
    int wb = b - (CSB + DEG4B);
    if (wb < 64)       wfuse_body(w0, f0, slots + 0, DI, DH, 8, wb,      red);
    else if (wb < 80)  wfuse_body(w1, f1, slots + 1, DH, DH, 8, wb - 64, red);
    else               wfuse_body(w2, f2, slots + 2, DH, DO, 3, wb - 80, red);
  }
}

// ---- MEGA-2: scan_blocks [0,196) || mean_finalize [196,198) ----------------
__global__ void scan_mean(const uint32_t* __restrict__ deg,
                          uint32_t* __restrict__ rowptr,
                          uint32_t* __restrict__ bsum,
                          double* __restrict__ dinv,
                          double* __restrict__ colsum) {
  __shared__ uint32_t bs[256];
  int b = blockIdx.x;
  int t = threadIdx.x;
  if (b < NBLK) {
    int i = b * 256 + t;
    uint32_t v = (i < NN) ? deg[i] : 0u;
    if (i < NN) dinv[i] = 1.0 / sqrt((double)(v + 1u));   // +1 self-loop
    bs[t] = v;
    __syncthreads();
    for (int ofs = 1; ofs < 256; ofs <<= 1) {
      uint32_t add = (t >= ofs) ? bs[t - ofs] : 0u;
      __syncthreads();
      bs[t] += add;
      __syncthreads();
    }
    if (i < NN) rowptr[i] = bs[t] - v;     // exclusive within block (pre-base)
    if (t == 255) bsum[b] = bs[255];
  } else {
    int c = (b - NBLK) * 256 + t;
    if (c < DI) colsum[c] = colsum[c] / (double)NN;
  }
}

__global__ void scan_bsum(const uint32_t* __restrict__ bsum,
                          uint32_t* __restrict__ base) {
  __shared__ uint32_t bs[256];
  int t = threadIdx.x;
  uint32_t v = (t < NBLK) ? bsum[t] : 0u;
  bs[t] = v;
  __syncthreads();
  for (int ofs = 1; ofs < 256; ofs <<= 1) {
    uint32_t add = (t >= ofs) ? bs[t - ofs] : 0u;
    __syncthreads();
    bs[t] += add;
    __syncthreads();
  }
  if (t < NBLK) base[t] = bs[t] - v;
}

// ---- MEGA-3: csr4 [0,586) || gemm0 [586,1368) ------------------------------
// csr: 4 edges/thread — 2 int4 loads + 4 independent atomic+scatter chains.
// Segment-internal edge order is atomic-nondeterministic (accepted since r2).
// gemm0 reads B-fragments from global (L2-resident 64KB); no LDS (r8 fix).
__global__ void csr_gemm0(const int* __restrict__ ei,
                          const uint32_t* __restrict__ rowptr,
                          const uint32_t* __restrict__ base,
                          uint32_t* __restrict__ cursor,
                          int* __restrict__ csr_src,
                          const float* __restrict__ x,
                          const double* __restrict__ mean,
                          const uint32_t* __restrict__ frag,
                          int8_t* __restrict__ H) {
  if (blockIdx.x < DEG4B) {
    int idx = blockIdx.x * 256 + threadIdx.x;     // edge quad index
    if (idx < NE / 4) {
      int4 d4 = *(const int4*)(ei + 4 * idx);
      int4 s4 = *(const int4*)(ei + NE + 4 * idx);
      uint32_t p0 = rowptr[d4.x] + base[d4.x >> 8] + atomicAdd(&cursor[d4.x], 1u);
      uint32_t p1 = rowptr[d4.y] + base[d4.y >> 8] + atomicAdd(&cursor[d4.y], 1u);
      uint32_t p2 = rowptr[d4.z] + base[d4.z >> 8] + atomicAdd(&cursor[d4.z], 1u);
      uint32_t p3 = rowptr[d4.w] + base[d4.w >> 8] + atomicAdd(&cursor[d4.w], 1u);
      csr_src[p0] = s4.x;
      csr_src[p1] = s4.y;
      csr_src[p2] = s4.z;
      csr_src[p3] = s4.w;
    }
    return;
  }
  const int blk = blockIdx.x - DEG4B;
  const uint4* fg = (const uint4*)frag;
  const int lane = threadIdx.x & 63;
  const int wv = threadIdx.x >> 6;
  const int r0 = (blk * 4 + wv) * 16;
  if (r0 >= NN) return;
  const int m = lane & 15, q = lane >> 4;
  const float* xp = x + (size_t)(r0 + m) * DI + q * 16;
  const double* mp0 = mean + q * 16;
  int4v acc[8];
#pragma unroll
  for (int t = 0; t < 8; ++t) acc[t] = (int4v){0, 0, 0, 0};
#pragma unroll
  for (int s = 0; s < 8; ++s) {
    const float* xs = xp + s * 64;
    const double* mp = mp0 + s * 64;
    int4v a;
#pragma unroll
    for (int w4 = 0; w4 < 4; ++w4) {
      float4 f = *(const float4*)(xs + 4 * w4);
      double v0 = (double)f.x - mp[4 * w4 + 0];
      double v1 = (double)f.y - mp[4 * w4 + 1];
      double v2 = (double)f.z - mp[4 * w4 + 2];
      double v3 = (double)f.w - mp[4 * w4 + 3];
      uint32_t o = 0;
      o |= (uint8_t)(int8_t)((v0 > 0.0) ? 1 : ((v0 < 0.0) ? -1 : 0));
      o |= ((uint32_t)(uint8_t)(int8_t)((v1 > 0.0) ? 1 : ((v1 < 0.0) ? -1 : 0))) << 8;
      o |= ((uint32_t)(uint8_t)(int8_t)((v2 > 0.0) ? 1 : ((v2 < 0.0) ? -1 : 0))) << 16;
      o |= ((uint32_t)(uint8_t)(int8_t)((v3 > 0.0) ? 1 : ((v3 < 0.0) ? -1 : 0))) << 24;
      a[w4] = (int)o;
    }
#pragma unroll
    for (int t = 0; t < 8; ++t) {
      int4v b = *(const int4v*)&fg[(s * 8 + t) * 64 + lane];   // L2-resident
      acc[t] = __builtin_amdgcn_mfma_i32_16x16x64_i8(a, b, acc[t], 0, 0, 0);
    }
  }
  int8_t* hp = H + (size_t)r0 * DH;
#pragma unroll
  for (int t = 0; t < 8; ++t) {
    int n = t * 16 + m;
#pragma unroll
    for (int r = 0; r < 4; ++r)
      hp[(size_t)(q * 4 + r) * DH + n] = (int8_t)(acc[t][r] >> 1);
  }
}

// ---------------- ternary GEMM via MFMA i8 16x16x64 -----------------------
template <int STEPS, int NT, int C, int SHIFT>
__global__ void gemm_mfma(const int8_t* __restrict__ S,
                          const uint32_t* __restrict__ frag,
                          int8_t* __restrict__ H) {
  extern __shared__ uint4 lb[];
  const int tot = STEPS * NT * 64;
  const uint4* fg = (const uint4*)frag;
  for (int i = threadIdx.x; i < tot; i += 256) lb[i] = fg[i];
  __syncthreads();
  const int lane = threadIdx.x & 63;
  const int wv = threadIdx.x >> 6;
  const int r0 = (blockIdx.x * 4 + wv) * 16;
  if (r0 >= NN) return;                 // NN % 16 == 0
  const int m = lane & 15, q = lane >> 4;
  const int K = STEPS * 64;
  const int8_t* sp = S + (size_t)(r0 + m) * K + q * 16;
  int4v acc[NT];
#pragma unroll
  for (int t = 0; t < NT; ++t) acc[t] = (int4v){0, 0, 0, 0};
#pragma unroll
  for (int s = 0; s < STEPS; ++s) {
    int4v a = *(const int4v*)(sp + (size_t)s * 64);
#pragma unroll
    for (int t = 0; t < NT; ++t) {
      int4v b = *(const int4v*)&lb[(s * NT + t) * 64 + lane];
      acc[t] = __builtin_amdgcn_mfma_i32_16x16x64_i8(a, b, acc[t], 0, 0, 0);
    }
  }
  int8_t* hp = H + (size_t)r0 * C;
#pragma unroll
  for (int t = 0; t < NT; ++t) {
    int n = t * 16 + m;
    if (n < C) {
#pragma unroll
      for (int r = 0; r < 4; ++r)
        hp[(size_t)(q * 4 + r) * C + n] = (int8_t)(acc[t][r] >> SHIFT);
    }
  }
}

// ---- gather (C=128): ORDER-PRESERVING, 1-deep prefetch, base folded in ----
__global__ void gather128(const uint32_t* __restrict__ rowptr,
                          const uint32_t* __restrict__ base,
                          const int* __restrict__ csr_src,
                          const double* __restrict__ dinv,
                          const int8_t* __restrict__ H,
                          const float* __restrict__ b,
                          int8_t* __restrict__ Sout,
                          const double* __restrict__ wsum, double cnt,
                          uint32_t fk0, uint32_t fk1) {
  int d = (int)(((size_t)blockIdx.x * blockDim.x + threadIdx.x) >> 6);
  int lane = threadIdx.x & 63;
  if (d >= NN) return;
  const int g = lane >> 5, p = lane & 31;
  double a0 = 0.0, a1 = 0.0, a2 = 0.0, a3 = 0.0;
  const uint32_t e0 = rowptr[d] + base[d >> 8];
  const uint32_t e1 = (d + 1 < NN) ? (rowptr[d + 1] + base[(d + 1) >> 8]) : NE;
  const int L = (int)(e1 - e0) + 1;               // + self-loop (edge 0)
  for (int c0 = 0; c0 < L; c0 += 64) {
    const int n = min(64, L - c0);
    const int my = c0 + lane;
    int sidx = d;
    if (my > 0 && my < L) sidx = csr_src[e0 + my - 1];
    double wv = dinv[sidx];                       // sidx=d is valid fallback
    int t = 0;
    {
      int sA = 0, sB = 0; double wA = 0.0, wB = 0.0;
      uint32_t hA = 0, hB = 0;
      if (4 <= n) {                               // wave-uniform
        sA = __shfl(sidx, g);      wA = __shfl(wv, g);
        sB = __shfl(sidx, 2 + g);  wB = __shfl(wv, 2 + g);
        hA = *(const uint32_t*)(H + (size_t)sA * DH + 4 * p);
        hB = *(const uint32_t*)(H + (size_t)sB * DH + 4 * p);
      }
      for (; t + 4 <= n; t += 4) {
        const uint32_t cA = hA, cB = hB;
        const double vA = wA, vB = wB;
        if (t + 8 <= n) {                         // prefetch next pair
          sA = __shfl(sidx, t + 4 + g);  wA = __shfl(wv, t + 4 + g);
          sB = __shfl(sidx, t + 6 + g);  wB = __shfl(wv, t + 6 + g);
          hA = *(const uint32_t*)(H + (size_t)sA * DH + 4 * p);
          hB = *(const uint32_t*)(H + (size_t)sB * DH + 4 * p);
        }
        a0 += vA * (double)(int8_t)(cA);
        a1 += vA * (double)(int8_t)(cA >> 8);
        a2 += vA * (double)(int8_t)(cA >> 16);
        a3 += vA * (double)(int8_t)(cA >> 24);
        a0 += vB * (double)(int8_t)(cB);
        a1 += vB * (double)(int8_t)(cB >> 8);
        a2 += vB * (double)(int8_t)(cB >> 16);
        a3 += vB * (double)(int8_t)(cB >> 24);
      }
    }
    for (; t < n; t += 2) {                       // non-divergent tail
      const int j = t + g;
      const bool on = (j < n);
      const int jc = on ? j : 0;
      int s = __shfl(sidx, jc);
      double w = __shfl(wv, jc);
      w = on ? w : 0.0;
      uint32_t hv = *(const uint32_t*)(H + (size_t)s * DH + 4 * p);
      a0 += w * (double)(int8_t)(hv);
      a1 += w * (double)(int8_t)(hv >> 8);
      a2 += w * (double)(int8_t)(hv >> 16);
      a3 += w * (double)(int8_t)(hv >> 24);
    }
  }
  a0 += __shfl_xor(a0, 32);
  a1 += __shfl_xor(a1, 32);
  a2 += __shfl_xor(a2, 32);
  a3 += __shfl_xor(a3, 32);
  double sc = (wsum[0] / cnt) * dinv[d];
  int ch = 4 * p + 2 * g;
  int j0 = d * DH + ch;
  double va = sc * ((g == 0) ? a0 : a2) + (double)b[ch];
  double vb = sc * ((g == 0) ? a1 : a3) + (double)b[ch + 1];
  int s0 = (va > 0.0) ? 1 : ((va < 0.0) ? -1 : 0);
  int s1 = (vb > 0.0) ? 1 : ((vb < 0.0) ? -1 : 0);
  uint32_t r0, r1, bits0, bits1;
  threefry2x32(fk0, fk1, 0u, (uint32_t)j0, &r0, &r1);
  bits0 = r0 ^ r1;
  threefry2x32(fk0, fk1, 0u, (uint32_t)(j0 + 1), &r0, &r1);
  bits1 = r0 ^ r1;
  float u0 = __uint_as_float((bits0 >> 9) | 0x3f800000u) - 1.0f;
  float u1 = __uint_as_float((bits1 >> 9) | 0x3f800000u) - 1.0f;
  uint8_t o0 = (u0 < 0.5f) ? (uint8_t)(int8_t)s0 : (uint8_t)0;
  uint8_t o1 = (u1 < 0.5f) ? (uint8_t)(int8_t)s1 : (uint8_t)0;
  *(uint16_t*)(Sout + j0) = (uint16_t)(o0 | ((uint16_t)o1 << 8));
}

// ---- gather (C=40): ORDER-PRESERVING, base folded in, fused log_softmax ---
__global__ void gather40_lsm(const uint32_t* __restrict__ rowptr,
                             const uint32_t* __restrict__ base,
                             const int* __restrict__ csr_src,
                             const double* __restrict__ dinv,
                             const int8_t* __restrict__ H,
                             const float* __restrict__ b2,
                             const double* __restrict__ wsum,
                             float* __restrict__ out) {
  int d = (int)(((size_t)blockIdx.x * blockDim.x + threadIdx.x) >> 6);
  int lane = threadIdx.x & 63;
  if (d >= NN) return;
  const int g = lane >> 5, p = lane & 31;
  const bool act = (p < 20);
  double a0 = 0.0, a1 = 0.0;
  const uint32_t e0 = rowptr[d] + base[d >> 8];
  const uint32_t e1 = (d + 1 < NN) ? (rowptr[d + 1] + base[(d + 1) >> 8]) : NE;
  const int L = (int)(e1 - e0) + 1;
  for (int c0 = 0; c0 < L; c0 += 64) {
    const int n = min(64, L - c0);
    const int my = c0 + lane;
    int sidx = d;
    if (my > 0 && my < L) sidx = csr_src[e0 + my - 1];
    double wv = dinv[sidx];
    int t = 0;
    {
      int sA = 0, sB = 0; double wA = 0.0, wB = 0.0;
      uint16_t hA = 0, hB = 0;
      if (4 <= n) {
        sA = __shfl(sidx, g);      wA = __shfl(wv, g);
        sB = __shfl(sidx, 2 + g);  wB = __shfl(wv, 2 + g);
        if (act) {
          hA = *(const uint16_t*)(H + (size_t)sA * DO + 2 * p);
          hB = *(const uint16_t*)(H + (size_t)sB * DO + 2 * p);
        }
      }
      for (; t + 4 <= n; t += 4) {
        const uint16_t cA = hA, cB = hB;
        const double vA = wA, vB = wB;
        if (t + 8 <= n) {
          sA = __shfl(sidx, t + 4 + g);  wA = __shfl(wv, t + 4 + g);
          sB = __shfl(sidx, t + 6 + g);  wB = __shfl(wv, t + 6 + g);
          if (act) {
            hA = *(const uint16_t*)(H + (size_t)sA * DO + 2 * p);
            hB = *(const uint16_t*)(H + (size_t)sB * DO + 2 * p);
          }
        }
        if (act) {
          a0 += vA * (double)(int8_t)(cA);
          a1 += vA * (double)(int8_t)(cA >> 8);
          a0 += vB * (double)(int8_t)(cB);
          a1 += vB * (double)(int8_t)(cB >> 8);
        }
      }
    }
    for (; t < n; t += 2) {
      const int j = t + g;
      const bool on = (j < n);
      const int jc = on ? j : 0;
      int s = __shfl(sidx, jc);
      double w = __shfl(wv, jc);
      w = on ? w : 0.0;
      if (act) {
        uint16_t hv = *(const uint16_t*)(H + (size_t)s * DO + 2 * p);
        a0 += w * (double)(int8_t)(hv);
        a1 += w * (double)(int8_t)(hv >> 8);
      }
    }
  }
  a0 += __shfl_xor(a0, 32);
  a1 += __shfl_xor(a1, 32);
  double sc = (wsum[0] / (double)(DH * DO)) * dinv[d];
  const bool lead = (g == 0) && act;
  double v0 = 0.0, v1 = 0.0;
  if (act) {
    v0 = sc * a0 + (double)b2[2 * p];
    v1 = sc * a1 + (double)b2[2 * p + 1];
  }
  double mx = lead ? fmax(v0, v1) : -1.0e300;
  for (int ofs = 32; ofs > 0; ofs >>= 1) mx = fmax(mx, __shfl_xor(mx, ofs));
  float ex = lead ? (expf((float)(v0 - mx)) + expf((float)(v1 - mx))) : 0.f;
  for (int ofs = 32; ofs > 0; ofs >>= 1) ex += __shfl_xor(ex, ofs);
  float l = logf(ex);
  if (lead) {
    float2 o = make_float2((float)(v0 - mx) - l, (float)(v1 - mx) - l);
    *(float2*)(out + (size_t)d * DO + 2 * p) = o;
  }
}

// ---------------- launch ----------------
extern "C" void kernel_launch(void* const* d_in, const int* in_sizes, int n_in,
                              void* d_out, int out_size, void* d_ws, size_t ws_size,
                              hipStream_t stream) {
  (void)in_sizes; (void)n_in; (void)out_size; (void)ws_size;
  const float* x  = (const float*)d_in[0];
  const int*   ei = (const int*)d_in[1];
  const float* w0 = (const float*)d_in[2];
  const float* b0 = (const float*)d_in[3];
  const float* w1 = (const float*)d_in[4];
  const float* b1 = (const float*)d_in[5];
  const float* w2 = (const float*)d_in[6];
  const float* b2 = (const float*)d_in[7];
  float* out = (float*)d_out;

  // ---- workspace carve-up (~17 MB)
  char* wsb = (char*)d_ws;
  double*   mean_d = (double*)wsb;                    // [512] col sums->means
  double*   wsum_d = (double*)(wsb + 4096);           // [3]            pad->4224
  uint32_t* deg_e  = (uint32_t*)(wsb + 4224);         // [NN] edge-only degree
  uint32_t* cursor = (uint32_t*)(wsb + 204224);       // [NN] fill cursors
  // bytes [0, 404224) are zeroed each call
  size_t cur = 404480;
  uint32_t* rowptr = (uint32_t*)(wsb + cur); cur += 200064;   // [NN+1] (pre-base)
  double*   dinv_d = (double*)(wsb + cur);  cur += 400000;
  cur = (cur + 255) & ~255ull;
  uint32_t* bsum = (uint32_t*)(wsb + cur); cur += 1024;       // [NBLK]
  uint32_t* base = (uint32_t*)(wsb + cur); cur += 1024;       // [NBLK]
  int*    csr_src = (int*)(wsb + cur);    cur += (size_t)NE * 4;   // 2.4 MB
  cur = (cur + 255) & ~255ull;
  uint32_t* FR0 = (uint32_t*)(wsb + cur); cur += 8 * 8 * 64 * 16;  // 64 KB
  uint32_t* FR1 = (uint32_t*)(wsb + cur); cur += 2 * 8 * 64 * 16;  // 16 KB
  uint32_t* FR2 = (uint32_t*)(wsb + cur); cur += 2 * 3 * 64 * 16;  // 6 KB
  int8_t* S1  = (int8_t*)(wsb + cur); cur += (size_t)MTOT;         // 6.4 MB
  cur = (cur + 255) & ~255ull;
  int8_t* H8 = (int8_t*)(wsb + cur); cur += (size_t)MTOT;          // 6.4 MB

  // fold_in(key(42), i): key=(0,42); folded = threefry(key, (0,i)) full output
  uint32_t fkA0, fkA1, fkB0, fkB1;
  threefry2x32(0u, 42u, 0u, 0u, &fkA0, &fkA1);
  threefry2x32(0u, 42u, 0u, 1u, &fkB0, &fkB1);

  // zero mean/wsum/deg/cursor (ws is poisoned 0xAA before every call)
  hipMemsetAsync(wsb, 0, 404224, stream);

  // MEGA-1: colsum || deg4 || wfuse  (1072 blocks)
  prologue_fused<<<CSB + DEG4B + 86, 256, 0, stream>>>(
      x, mean_d, ei, deg_e, w0, w1, w2, FR0, FR1, FR2, wsum_d);
  // MEGA-2: scan_blocks || mean_finalize  (198 blocks)
  scan_mean<<<NBLK + 2, 256, 0, stream>>>(deg_e, rowptr, bsum, dinv_d, mean_d);
  scan_bsum<<<1, 256, 0, stream>>>(bsum, base);

  const int node_blocks = (NN * 64) / 256 + 1;          // 12501 waves >= NN
  const size_t sh1 = 2 * 8 * 64 * 16;                   // 16 KB
  const size_t sh2 = 2 * 3 * 64 * 16;                   // 6 KB

  // MEGA-3: csr4 || gemm0(bn_sign fused), NO LDS
  csr_gemm0<<<DEG4B + GEMMB, 256, 0, stream>>>(ei, rowptr, base, cursor,
                                               csr_src, x, mean_d, FR0, H8);
  gather128<<<node_blocks, 256, 0, stream>>>(rowptr, base, csr_src, dinv_d, H8,
                                             b0, S1, wsum_d + 0,
                                             (double)(DI * DH / 2), fkA0, fkA1);

  // layer 1: K=128 -> DH
  gemm_mfma<2, 8, DH, 0><<<GEMMB, 256, sh1, stream>>>(S1, FR1, H8);
  gather128<<<node_blocks, 256, 0, stream>>>(rowptr, base, csr_src, dinv_d, H8,
                                             b1, S1, wsum_d + 1,
                                             (double)(DH * DH), fkB0, fkB1);

  // layer 2: K=128 -> DO, fused log_softmax
  gemm_mfma<2, 3, DO, 0><<<GEMMB, 256, sh2, stream>>>(S1, FR2, H8);
  gather40_lsm<<<node_blocks, 256, 0, stream>>>(rowptr, base, csr_src, dinv_d,
                                                H8, b2, wsum_d + 2, out);
}